// Round 3
// baseline (2768.306 us; speedup 1.0000x reference)
//
#include <hip/hip_runtime.h>
#include <cstdint>
#include <cstddef>

#define IN_C 128
#define HIDc 128
#define OUTc 64

// ---- bf16 helpers (RNE) ----
__device__ __forceinline__ unsigned short f2bf(float f) {
    unsigned int u = __float_as_uint(f);
    unsigned int r = (u + 0x7FFFu + ((u >> 16) & 1u)) >> 16;
    return (unsigned short)r;
}
__device__ __forceinline__ float bf2f(unsigned short h) {
    return __uint_as_float(((unsigned int)h) << 16);
}

// ---------------------------------------------------------------------------
// Edge dtype detection: reference declares int64 but the harness may hand us
// int32. Read first 64 elements as int64; all in [0, N) => genuinely int64.
// ---------------------------------------------------------------------------
__global__ void k_detect(const long long* ei, int n_nodes, int* flag) {
    int t = threadIdx.x;                    // blockDim = 64
    long long v = ei[t];
    int ok = (v >= 0 && v < (long long)n_nodes) ? 1 : 0;
    unsigned long long m = __ballot(ok);
    if (t == 0) *flag = (m == ~0ull) ? 1 : 0;
}

__global__ void k_cvt_edges(const void* ei, int twoE, const int* flag, int* out) {
    int i = blockIdx.x * blockDim.x + threadIdx.x;
    if (i >= twoE) return;
    if (*flag) out[i] = (int)((const long long*)ei)[i];
    else       out[i] = ((const int*)ei)[i];
}

__global__ void k_hist(const int* __restrict__ eint, int E, int* __restrict__ deg, int n) {
    int e = blockIdx.x * blockDim.x + threadIdx.x;
    if (e >= E) return;
    int c = eint[E + e];
    if ((unsigned)c < (unsigned)n) atomicAdd(&deg[c], 1);
}

__global__ void k_dinv(const int* __restrict__ deg, float* __restrict__ dinv, int n) {
    int i = blockIdx.x * blockDim.x + threadIdx.x;
    if (i < n) dinv[i] = (deg[i] > 0) ? rsqrtf((float)deg[i]) : 0.0f;
}

// Allocate contiguous CSR ranges per node: wave-level scan + one atomic/wave.
__global__ void k_alloc(const int* __restrict__ deg, int* __restrict__ base,
                        int* __restrict__ cursor, int* __restrict__ counter, int n) {
    int i = blockIdx.x * blockDim.x + threadIdx.x;
    int lane = threadIdx.x & 63;
    int val = (i < n) ? deg[i] : 0;
    int scan = val;
    #pragma unroll
    for (int off = 1; off < 64; off <<= 1) {
        int t = __shfl_up(scan, off);
        if (lane >= off) scan += t;
    }
    int excl = scan - val;
    int total = __shfl(scan, 63);
    int wb = 0;
    if (lane == 0) wb = atomicAdd(counter, total);
    wb = __shfl(wb, 0);
    if (i < n) { base[i] = wb + excl; cursor[i] = wb + excl; }
}

__global__ void k_scatter(const int* __restrict__ eint, int E,
                          const float* __restrict__ dinv, int n,
                          int* __restrict__ cursor,
                          int* __restrict__ csr_src, float* __restrict__ csr_w) {
    int e = blockIdx.x * blockDim.x + threadIdx.x;
    if (e >= E) return;
    int r = eint[e];
    int c = eint[E + e];
    if ((unsigned)r >= (unsigned)n || (unsigned)c >= (unsigned)n) return;
    int p = atomicAdd(&cursor[c], 1);
    csr_src[p] = r;
    csr_w[p]   = dinv[r] * dinv[c];
}

// ---------------------------------------------------------------------------
// SpMM: gather fp32 rows, store fp32 or bf16.
// block = (64, 4); one wave per node; V floats/lane (V=2 -> 128 cols, V=1 -> 64).
// ---------------------------------------------------------------------------
template<int V, bool BFOUT>
__global__ __launch_bounds__(256) void k_spmm(
    const float* __restrict__ S, void* __restrict__ Dv, int width,
    const int* __restrict__ base, const int* __restrict__ deg,
    const int* __restrict__ src, const float* __restrict__ w, int n)
{
    int node = blockIdx.x * blockDim.y + threadIdx.y;
    if (node >= n) return;
    int tx = threadIdx.x;
    float acc[V];
    #pragma unroll
    for (int v = 0; v < V; v++) acc[v] = 0.0f;
    int b = base[node], d = deg[node];
    const float* Sp = S + tx * V;
    for (int e = b; e < b + d; ++e) {
        int s = src[e];
        float we = w[e];
        const float* r = Sp + (size_t)s * width;
        if (V == 2) {
            float2 xv = *(const float2*)r;
            acc[0] += we * xv.x; acc[1] += we * xv.y;
        } else {
            acc[0] += we * r[0];
        }
    }
    if (BFOUT) {
        unsigned short* D = (unsigned short*)Dv;
        if (V == 2) {
            ushort2 o; o.x = f2bf(acc[0]); o.y = f2bf(acc[1]);
            *(ushort2*)&D[(size_t)node * width + tx * 2] = o;
        } else {
            D[(size_t)node * width + tx] = f2bf(acc[0]);
        }
    } else {
        float* D = (float*)Dv;
        #pragma unroll
        for (int v = 0; v < V; v++) D[(size_t)node * width + tx * V + v] = acc[v];
    }
}

// ---------------------------------------------------------------------------
// fp32 tiled GEMM, piecewise A (3 fp32 pieces of width W, ld == W):
//   C = concat(A0,A1,A2)(MxK) @ B(KxNcols) + bias
// block 256, tile 64x64, BK=16, 4x4 per thread.
// ---------------------------------------------------------------------------
__global__ __launch_bounds__(256) void k_gemm64p(
    const float* __restrict__ A0, const float* __restrict__ A1,
    const float* __restrict__ A2, int W, int M,
    const float* __restrict__ B, int ldb, int K,
    const float* __restrict__ bias,
    float* __restrict__ C, int ldc)
{
    __shared__ __align__(16) float As[16][64];
    __shared__ __align__(16) float Bs[16][64];
    int t  = threadIdx.x;
    int tx = t & 15, ty = t >> 4;
    int row0 = blockIdx.x * 64, col0 = blockIdx.y * 64;
    float acc[4][4] = {{0.f}};
    int am = t >> 2;          // 0..63
    int ak = (t & 3) * 4;     // 0,4,8,12
    int bk = t >> 4;          // 0..15
    int bc = (t & 15) * 4;    // 0..60

    for (int k0 = 0; k0 < K; k0 += 16) {
        int pi = k0 / W;
        const float* Ap = (pi == 0) ? A0 : ((pi == 1) ? A1 : A2);
        int kl = k0 - pi * W;
        int arow = row0 + am; if (arow >= M) arow = M - 1;   // clamp (stores guarded)
        float4 a  = *(const float4*)&Ap[(size_t)arow * W + kl + ak];
        float4 bv = *(const float4*)&B[(size_t)(k0 + bk) * ldb + col0 + bc];
        __syncthreads();
        As[ak + 0][am] = a.x; As[ak + 1][am] = a.y;
        As[ak + 2][am] = a.z; As[ak + 3][am] = a.w;
        *(float4*)&Bs[bk][bc] = bv;
        __syncthreads();
        #pragma unroll
        for (int k = 0; k < 16; k++) {
            float av[4], bw[4];
            *(float4*)av = *(const float4*)&As[k][ty * 4];
            *(float4*)bw = *(const float4*)&Bs[k][tx * 4];
            #pragma unroll
            for (int i = 0; i < 4; i++)
                #pragma unroll
                for (int j = 0; j < 4; j++)
                    acc[i][j] += av[i] * bw[j];
        }
    }
    #pragma unroll
    for (int i = 0; i < 4; i++) {
        int r = row0 + ty * 4 + i;
        if (r >= M) continue;
        #pragma unroll
        for (int j = 0; j < 4; j++) {
            int c = col0 + tx * 4 + j;
            C[(size_t)r * ldc + c] = acc[i][j] + bias[c];
        }
    }
}

// Same, but A pieces are bf16 (ushort); compute/accumulate fp32.
__global__ __launch_bounds__(256) void k_gemm64p_bf(
    const unsigned short* __restrict__ A0, const unsigned short* __restrict__ A1,
    const unsigned short* __restrict__ A2, int W, int M,
    const float* __restrict__ B, int ldb, int K,
    const float* __restrict__ bias,
    float* __restrict__ C, int ldc)
{
    __shared__ __align__(16) float As[16][64];
    __shared__ __align__(16) float Bs[16][64];
    int t  = threadIdx.x;
    int tx = t & 15, ty = t >> 4;
    int row0 = blockIdx.x * 64, col0 = blockIdx.y * 64;
    float acc[4][4] = {{0.f}};
    int am = t >> 2;
    int ak = (t & 3) * 4;
    int bk = t >> 4;
    int bc = (t & 15) * 4;

    for (int k0 = 0; k0 < K; k0 += 16) {
        int pi = k0 / W;
        const unsigned short* Ap = (pi == 0) ? A0 : ((pi == 1) ? A1 : A2);
        int kl = k0 - pi * W;
        int arow = row0 + am; if (arow >= M) arow = M - 1;
        ushort4 a4 = *(const ushort4*)&Ap[(size_t)arow * W + kl + ak];
        float4 bv = *(const float4*)&B[(size_t)(k0 + bk) * ldb + col0 + bc];
        __syncthreads();
        As[ak + 0][am] = bf2f(a4.x); As[ak + 1][am] = bf2f(a4.y);
        As[ak + 2][am] = bf2f(a4.z); As[ak + 3][am] = bf2f(a4.w);
        *(float4*)&Bs[bk][bc] = bv;
        __syncthreads();
        #pragma unroll
        for (int k = 0; k < 16; k++) {
            float av[4], bw[4];
            *(float4*)av = *(const float4*)&As[k][ty * 4];
            *(float4*)bw = *(const float4*)&Bs[k][tx * 4];
            #pragma unroll
            for (int i = 0; i < 4; i++)
                #pragma unroll
                for (int j = 0; j < 4; j++)
                    acc[i][j] += av[i] * bw[j];
        }
    }
    #pragma unroll
    for (int i = 0; i < 4; i++) {
        int r = row0 + ty * 4 + i;
        if (r >= M) continue;
        #pragma unroll
        for (int j = 0; j < 4; j++) {
            int c = col0 + tx * 4 + j;
            C[(size_t)r * ldc + c] = acc[i][j] + bias[c];
        }
    }
}

// ---------------------------------------------------------------------------
// BatchNorm (training batch stats) over concat of 3 N x 128 pieces:
//   piece0 = fp32 (F0), piece1/2 = bf16 (H1, H2). blockDim = 384.
// ---------------------------------------------------------------------------
__global__ void k_bnstats(const float* __restrict__ F0,
                          const unsigned short* __restrict__ H1,
                          const unsigned short* __restrict__ H2,
                          float* __restrict__ sums, float* __restrict__ sumsq, int n)
{
    int c = threadIdx.x;
    int cc = c & 127;
    int pi = c >> 7;
    float s = 0.f, s2 = 0.f;
    if (pi == 0) {
        for (int r = blockIdx.x; r < n; r += gridDim.x) {
            float v = F0[(size_t)r * 128 + cc]; s += v; s2 += v * v;
        }
    } else {
        const unsigned short* H = (pi == 1) ? H1 : H2;
        for (int r = blockIdx.x; r < n; r += gridDim.x) {
            float v = bf2f(H[(size_t)r * 128 + cc]); s += v; s2 += v * v;
        }
    }
    atomicAdd(&sums[c], s);
    atomicAdd(&sumsq[c], s2);
}

__global__ void k_bnfin(const float* __restrict__ sums, const float* __restrict__ sumsq,
                        const float* __restrict__ g, const float* __restrict__ bb,
                        float* __restrict__ scale, float* __restrict__ shift,
                        int cat, float invn)
{
    int c = threadIdx.x;
    if (c >= cat) return;
    float mu  = sums[c] * invn;
    float var = sumsq[c] * invn - mu * mu;
    float sc  = g[c] * rsqrtf(var + 1e-5f);
    scale[c] = sc;
    shift[c] = bb[c] - mu * sc;
}

// Apply BN+ReLU: piece0 F0(fp32) -> H0(bf16); pieces 1/2 in-place bf16.
__global__ void k_bnapply(const float* __restrict__ F0, unsigned short* __restrict__ H0,
                          unsigned short* __restrict__ H1, unsigned short* __restrict__ H2,
                          const float* __restrict__ scale, const float* __restrict__ shift,
                          int n)
{
    int c = threadIdx.x;              // 384
    int cc = c & 127;
    int pi = c >> 7;
    float sc = scale[c], sh = shift[c];
    if (pi == 0) {
        for (int r = blockIdx.x; r < n; r += gridDim.x) {
            size_t idx = (size_t)r * 128 + cc;
            float v = F0[idx] * sc + sh;
            H0[idx] = f2bf(fmaxf(v, 0.0f));
        }
    } else {
        unsigned short* H = (pi == 1) ? H1 : H2;
        for (int r = blockIdx.x; r < n; r += gridDim.x) {
            size_t idx = (size_t)r * 128 + cc;
            float v = bf2f(H[idx]) * sc + sh;
            H[idx] = f2bf(fmaxf(v, 0.0f));
        }
    }
}

// Diagnostic: if workspace is too small, surface ws_size (MB) via d_out.
__global__ void k_diag(float* out, float val, int n) {
    int i = blockIdx.x * blockDim.x + threadIdx.x;
    if (i < n) out[i] = val;
}

// ---------------------------------------------------------------------------
extern "C" void kernel_launch(void* const* d_in, const int* in_sizes, int n_in,
                              void* d_out, int out_size, void* d_ws, size_t ws_size,
                              hipStream_t stream)
{
    const float* x    = (const float*)d_in[0];
    const void*  ei   = d_in[1];
    const float* W0   = (const float*)d_in[2];
    const float* b0   = (const float*)d_in[3];
    const float* W1   = (const float*)d_in[4];
    const float* b1   = (const float*)d_in[5];
    const float* W2   = (const float*)d_in[6];
    const float* b2   = (const float*)d_in[7];
    const float* bn0g = (const float*)d_in[8];
    const float* bn0b = (const float*)d_in[9];
    const float* bn1g = (const float*)d_in[10];
    const float* bn1b = (const float*)d_in[11];
    const float* fpW  = (const float*)d_in[12];
    const float* fpb  = (const float*)d_in[13];
    float* out = (float*)d_out;

    const int N    = in_sizes[0] / IN_C;
    const int twoE = in_sizes[1];
    const int E    = twoE / 2;

    // ---- workspace carve (~258 MB; ws is 256 MiB = 268.4 MB) ----
    char* p = (char*)d_ws;
    auto alloc = [&](size_t bytes) -> char* {
        char* r = p; p += (bytes + 255) & ~(size_t)255; return r;
    };
    float* F0 = (float*)alloc((size_t)N * 128 * 4);        // 51.2 MB
    float* F1 = (float*)alloc((size_t)N * 128 * 4);
    float* F2 = (float*)alloc((size_t)N * 128 * 4);
    unsigned short* H0 = (unsigned short*)alloc((size_t)N * 128 * 2);  // 25.6 MB
    unsigned short* H1 = (unsigned short*)alloc((size_t)N * 128 * 2);
    unsigned short* H2 = (unsigned short*)alloc((size_t)N * 128 * 2);
    float* dinv  = (float*)alloc((size_t)N * 4);
    float* csrw  = (float*)alloc((size_t)E * 4);
    float* sums  = (float*)alloc(2 * 384 * 4);
    float* sumsq = sums + 384;
    float* scale = (float*)alloc(384 * 4);
    float* shift = (float*)alloc(384 * 4);
    int* deg     = (int*)alloc((size_t)N * 4);
    int* base    = (int*)alloc((size_t)N * 4);
    int* cursor  = (int*)alloc((size_t)N * 4);
    int* csrsrc  = (int*)alloc((size_t)E * 4);
    int* eint    = (int*)alloc((size_t)twoE * 4);
    int* counter = (int*)alloc(4);
    int* flag    = (int*)alloc(4);

    size_t required = (size_t)(p - (char*)d_ws);
    if (required > ws_size) {
        k_diag<<<(out_size + 255) / 256, 256, 0, stream>>>(
            out, (float)(ws_size >> 20), out_size);
        return;
    }

    // Layer-2 fp32 64-wide buffers overlay the F region (6 x 25.6 MB).
    float* L0 = F0;
    float* L1 = F0 + (size_t)N * 64;
    float* L2 = F1;
    float* L3 = F1 + (size_t)N * 64;
    float* L4 = F2;
    float* L5 = F2 + (size_t)N * 64;

    const int T = 256;
    dim3 spmm_blk(64, 4);
    int  spmm_grid = (N + 3) / 4;
    int  gx = (N + 63) / 64;

    // ---- graph build ----
    hipMemsetAsync(deg, 0, (size_t)N * 4, stream);
    hipMemsetAsync(counter, 0, 4, stream);
    k_detect<<<1, 64, 0, stream>>>((const long long*)ei, N, flag);
    k_cvt_edges<<<(twoE + T - 1) / T, T, 0, stream>>>(ei, twoE, flag, eint);
    k_hist<<<(E + T - 1) / T, T, 0, stream>>>(eint, E, deg, N);
    k_dinv<<<(N + T - 1) / T, T, 0, stream>>>(deg, dinv, N);
    k_alloc<<<(N + T - 1) / T, T, 0, stream>>>(deg, base, cursor, counter, N);
    k_scatter<<<(E + T - 1) / T, T, 0, stream>>>(eint, E, dinv, N, cursor, csrsrc, csrw);

    // ---- layer 0: x (fp32) -> G0,G1,G2 in F0,F1,F2 ----
    for (int j = 0; j < 3; j++) {
        float* Fj = (j == 0) ? F0 : ((j == 1) ? F1 : F2);
        k_gemm64p<<<dim3(gx, 2), T, 0, stream>>>(x, x, x, IN_C, N,
            W0 + (size_t)j * IN_C * HIDc, HIDc, IN_C, b0 + j * HIDc, Fj, HIDc);
    }
    // out1 = A*F1 -> H1 (bf16); t = A*F2 -> F1; out2 = A*F1 -> H2 (bf16)
    k_spmm<2, true ><<<spmm_grid, spmm_blk, 0, stream>>>(F1, H1, 128, base, deg, csrsrc, csrw, N);
    k_spmm<2, false><<<spmm_grid, spmm_blk, 0, stream>>>(F2, F1, 128, base, deg, csrsrc, csrw, N);
    k_spmm<2, true ><<<spmm_grid, spmm_blk, 0, stream>>>(F1, H2, 128, base, deg, csrsrc, csrw, N);
    hipMemsetAsync(sums, 0, 2 * 384 * 4, stream);
    k_bnstats<<<2048, 384, 0, stream>>>(F0, H1, H2, sums, sumsq, N);
    k_bnfin<<<1, 384, 0, stream>>>(sums, sumsq, bn0g, bn0b, scale, shift, 384, 1.0f / N);
    k_bnapply<<<2048, 384, 0, stream>>>(F0, H0, H1, H2, scale, shift, N);

    // ---- layer 1: H0,H1,H2 (bf16) -> F0,F1,F2 ----
    for (int j = 0; j < 3; j++) {
        float* Fj = (j == 0) ? F0 : ((j == 1) ? F1 : F2);
        k_gemm64p_bf<<<dim3(gx, 2), T, 0, stream>>>(H0, H1, H2, HIDc, N,
            W1 + (size_t)j * 384 * HIDc, HIDc, 384, b1 + j * HIDc, Fj, HIDc);
    }
    k_spmm<2, true ><<<spmm_grid, spmm_blk, 0, stream>>>(F1, H1, 128, base, deg, csrsrc, csrw, N);
    k_spmm<2, false><<<spmm_grid, spmm_blk, 0, stream>>>(F2, F1, 128, base, deg, csrsrc, csrw, N);
    k_spmm<2, true ><<<spmm_grid, spmm_blk, 0, stream>>>(F1, H2, 128, base, deg, csrsrc, csrw, N);
    hipMemsetAsync(sums, 0, 2 * 384 * 4, stream);
    k_bnstats<<<2048, 384, 0, stream>>>(F0, H1, H2, sums, sumsq, N);
    k_bnfin<<<1, 384, 0, stream>>>(sums, sumsq, bn1g, bn1b, scale, shift, 384, 1.0f / N);
    k_bnapply<<<2048, 384, 0, stream>>>(F0, H0, H1, H2, scale, shift, N);

    // ---- layer 2: H0,H1,H2 (bf16) -> 64-wide fp32 pieces ----
    {
        float* o[3] = { L0, L1, L2 };
        for (int j = 0; j < 3; j++)
            k_gemm64p_bf<<<dim3(gx, 1), T, 0, stream>>>(H0, H1, H2, HIDc, N,
                W2 + (size_t)j * 384 * OUTc, OUTc, 384, b2 + j * OUTc, o[j], OUTc);
    }
    // out1 = A*L1 -> L3; t = A*L2 -> L4; out2 = A*L4 -> L5
    k_spmm<1, false><<<spmm_grid, spmm_blk, 0, stream>>>(L1, L3, 64, base, deg, csrsrc, csrw, N);
    k_spmm<1, false><<<spmm_grid, spmm_blk, 0, stream>>>(L2, L4, 64, base, deg, csrsrc, csrw, N);
    k_spmm<1, false><<<spmm_grid, spmm_blk, 0, stream>>>(L4, L5, 64, base, deg, csrsrc, csrw, N);

    // ---- final projection: out = concat(L0, L3, L5) (N x 192) @ fpW + fpb ----
    k_gemm64p<<<dim3(gx, 1), T, 0, stream>>>(L0, L3, L5, OUTc, N,
        fpW, OUTc, 192, fpb, out, OUTc);
}

// Round 5
// 2287.306 us; speedup vs baseline: 1.2103x; 1.2103x over previous
//
#include <hip/hip_runtime.h>
#include <cstdint>
#include <cstddef>

#define IN_C 128
#define HIDc 128
#define OUTc 64

// ---- bf16 helpers (RNE) ----
__device__ __forceinline__ unsigned short f2bf(float f) {
    unsigned int u = __float_as_uint(f);
    unsigned int r = (u + 0x7FFFu + ((u >> 16) & 1u)) >> 16;
    return (unsigned short)r;
}
__device__ __forceinline__ float bf2f(unsigned short h) {
    return __uint_as_float(((unsigned int)h) << 16);
}

// ---------------------------------------------------------------------------
// Edge dtype detection (int64 vs int32 storage), conversion, graph build.
// (verbatim from round 3 — battle-tested)
// ---------------------------------------------------------------------------
__global__ void k_detect(const long long* ei, int n_nodes, int* flag) {
    int t = threadIdx.x;                    // blockDim = 64
    long long v = ei[t];
    int ok = (v >= 0 && v < (long long)n_nodes) ? 1 : 0;
    unsigned long long m = __ballot(ok);
    if (t == 0) *flag = (m == ~0ull) ? 1 : 0;
}

__global__ void k_cvt_edges(const void* ei, int twoE, const int* flag, int* out) {
    int i = blockIdx.x * blockDim.x + threadIdx.x;
    if (i >= twoE) return;
    if (*flag) out[i] = (int)((const long long*)ei)[i];
    else       out[i] = ((const int*)ei)[i];
}

__global__ void k_hist(const int* __restrict__ eint, int E, int* __restrict__ deg, int n) {
    int e = blockIdx.x * blockDim.x + threadIdx.x;
    if (e >= E) return;
    int c = eint[E + e];
    if ((unsigned)c < (unsigned)n) atomicAdd(&deg[c], 1);
}

__global__ void k_dinv(const int* __restrict__ deg, float* __restrict__ dinv, int n) {
    int i = blockIdx.x * blockDim.x + threadIdx.x;
    if (i < n) dinv[i] = (deg[i] > 0) ? rsqrtf((float)deg[i]) : 0.0f;
}

__global__ void k_alloc(const int* __restrict__ deg, int* __restrict__ base,
                        int* __restrict__ cursor, int* __restrict__ counter, int n) {
    int i = blockIdx.x * blockDim.x + threadIdx.x;
    int lane = threadIdx.x & 63;
    int val = (i < n) ? deg[i] : 0;
    int scan = val;
    #pragma unroll
    for (int off = 1; off < 64; off <<= 1) {
        int t = __shfl_up(scan, off);
        if (lane >= off) scan += t;
    }
    int excl = scan - val;
    int total = __shfl(scan, 63);
    int wb = 0;
    if (lane == 0) wb = atomicAdd(counter, total);
    wb = __shfl(wb, 0);
    if (i < n) { base[i] = wb + excl; cursor[i] = wb + excl; }
}

__global__ void k_scatter(const int* __restrict__ eint, int E,
                          const float* __restrict__ dinv, int n,
                          int* __restrict__ cursor,
                          int* __restrict__ csr_src, float* __restrict__ csr_w) {
    int e = blockIdx.x * blockDim.x + threadIdx.x;
    if (e >= E) return;
    int r = eint[e];
    int c = eint[E + e];
    if ((unsigned)r >= (unsigned)n || (unsigned)c >= (unsigned)n) return;
    int p = atomicAdd(&cursor[c], 1);
    csr_src[p] = r;
    csr_w[p]   = dinv[r] * dinv[c];
}

// ---------------------------------------------------------------------------
// fp32 tiled GEMM (round-3 verbatim, epilogue templated for bf16 out):
//   C = concat(A0,A1,A2)(M x K, fp32 pieces width W) @ B(K x Ncols, fp32) + bias
// block 256, tile 64x64, BK=16, 4x4 per thread.
// ---------------------------------------------------------------------------
template<bool BFOUT>
__global__ __launch_bounds__(256) void k_gemm64p(
    const float* __restrict__ A0, const float* __restrict__ A1,
    const float* __restrict__ A2, int W, int M,
    const float* __restrict__ B, int ldb, int K,
    const float* __restrict__ bias,
    void* __restrict__ Cv, int ldc)
{
    __shared__ __align__(16) float As[16][64];
    __shared__ __align__(16) float Bs[16][64];
    int t  = threadIdx.x;
    int tx = t & 15, ty = t >> 4;
    int row0 = blockIdx.x * 64, col0 = blockIdx.y * 64;
    float acc[4][4] = {{0.f}};
    int am = t >> 2;          // 0..63
    int ak = (t & 3) * 4;     // 0,4,8,12
    int bk = t >> 4;          // 0..15
    int bc = (t & 15) * 4;    // 0..60

    for (int k0 = 0; k0 < K; k0 += 16) {
        int pi = k0 / W;
        const float* Ap = (pi == 0) ? A0 : ((pi == 1) ? A1 : A2);
        int kl = k0 - pi * W;
        int arow = row0 + am; if (arow >= M) arow = M - 1;   // clamp (stores guarded)
        float4 a  = *(const float4*)&Ap[(size_t)arow * W + kl + ak];
        float4 bv = *(const float4*)&B[(size_t)(k0 + bk) * ldb + col0 + bc];
        __syncthreads();
        As[ak + 0][am] = a.x; As[ak + 1][am] = a.y;
        As[ak + 2][am] = a.z; As[ak + 3][am] = a.w;
        *(float4*)&Bs[bk][bc] = bv;
        __syncthreads();
        #pragma unroll
        for (int k = 0; k < 16; k++) {
            float av[4], bw[4];
            *(float4*)av = *(const float4*)&As[k][ty * 4];
            *(float4*)bw = *(const float4*)&Bs[k][tx * 4];
            #pragma unroll
            for (int i = 0; i < 4; i++)
                #pragma unroll
                for (int j = 0; j < 4; j++)
                    acc[i][j] += av[i] * bw[j];
        }
    }
    #pragma unroll
    for (int i = 0; i < 4; i++) {
        int r = row0 + ty * 4 + i;
        if (r >= M) continue;
        #pragma unroll
        for (int j = 0; j < 4; j++) {
            int c = col0 + tx * 4 + j;
            float v = acc[i][j] + bias[c];
            if (BFOUT) ((unsigned short*)Cv)[(size_t)r * ldc + c] = f2bf(v);
            else       ((float*)Cv)[(size_t)r * ldc + c] = v;
        }
    }
}

// Same, A pieces bf16 (round-3 verbatim + templated epilogue).
template<bool BFOUT>
__global__ __launch_bounds__(256) void k_gemm64p_bf(
    const unsigned short* __restrict__ A0, const unsigned short* __restrict__ A1,
    const unsigned short* __restrict__ A2, int W, int M,
    const float* __restrict__ B, int ldb, int K,
    const float* __restrict__ bias,
    void* __restrict__ Cv, int ldc)
{
    __shared__ __align__(16) float As[16][64];
    __shared__ __align__(16) float Bs[16][64];
    int t  = threadIdx.x;
    int tx = t & 15, ty = t >> 4;
    int row0 = blockIdx.x * 64, col0 = blockIdx.y * 64;
    float acc[4][4] = {{0.f}};
    int am = t >> 2;
    int ak = (t & 3) * 4;
    int bk = t >> 4;
    int bc = (t & 15) * 4;

    for (int k0 = 0; k0 < K; k0 += 16) {
        int pi = k0 / W;
        const unsigned short* Ap = (pi == 0) ? A0 : ((pi == 1) ? A1 : A2);
        int kl = k0 - pi * W;
        int arow = row0 + am; if (arow >= M) arow = M - 1;
        ushort4 a4 = *(const ushort4*)&Ap[(size_t)arow * W + kl + ak];
        float4 bv = *(const float4*)&B[(size_t)(k0 + bk) * ldb + col0 + bc];
        __syncthreads();
        As[ak + 0][am] = bf2f(a4.x); As[ak + 1][am] = bf2f(a4.y);
        As[ak + 2][am] = bf2f(a4.z); As[ak + 3][am] = bf2f(a4.w);
        *(float4*)&Bs[bk][bc] = bv;
        __syncthreads();
        #pragma unroll
        for (int k = 0; k < 16; k++) {
            float av[4], bw[4];
            *(float4*)av = *(const float4*)&As[k][ty * 4];
            *(float4*)bw = *(const float4*)&Bs[k][tx * 4];
            #pragma unroll
            for (int i = 0; i < 4; i++)
                #pragma unroll
                for (int j = 0; j < 4; j++)
                    acc[i][j] += av[i] * bw[j];
        }
    }
    #pragma unroll
    for (int i = 0; i < 4; i++) {
        int r = row0 + ty * 4 + i;
        if (r >= M) continue;
        #pragma unroll
        for (int j = 0; j < 4; j++) {
            int c = col0 + tx * 4 + j;
            float v = acc[i][j] + bias[c];
            if (BFOUT) ((unsigned short*)Cv)[(size_t)r * ldc + c] = f2bf(v);
            else       ((float*)Cv)[(size_t)r * ldc + c] = v;
        }
    }
}

// ---------------------------------------------------------------------------
// SpMM (bf16 in/out, fp32 accumulate). One wave per node.
// V bf16/lane: V=2 -> width 128, V=1 -> width 64.
// Dual-source variant gathers two matrices with one index/weight read.
// ---------------------------------------------------------------------------
template<int V>
__global__ __launch_bounds__(256) void k_spmm2(
    const unsigned short* __restrict__ S1, const unsigned short* __restrict__ S2,
    unsigned short* __restrict__ D1, unsigned short* __restrict__ D2, int width,
    const int* __restrict__ base, const int* __restrict__ deg,
    const int* __restrict__ src, const float* __restrict__ w, int n)
{
    int node = blockIdx.x * 4 + threadIdx.y;
    if (node >= n) return;
    int tx = threadIdx.x;
    float a1[V], a2[V];
    #pragma unroll
    for (int v = 0; v < V; v++) { a1[v] = 0.f; a2[v] = 0.f; }
    int b = base[node], d = deg[node];
    for (int e = b; e < b + d; ++e) {
        int s = src[e];
        float we = w[e];
        const unsigned short* r1 = S1 + (size_t)s * width + tx * V;
        const unsigned short* r2 = S2 + (size_t)s * width + tx * V;
        if (V == 2) {
            ushort2 x1 = *(const ushort2*)r1;
            ushort2 x2 = *(const ushort2*)r2;
            a1[0] += we * bf2f(x1.x); a1[1] += we * bf2f(x1.y);
            a2[0] += we * bf2f(x2.x); a2[1] += we * bf2f(x2.y);
        } else {
            a1[0] += we * bf2f(*r1);
            a2[0] += we * bf2f(*r2);
        }
    }
    size_t o = (size_t)node * width + tx * V;
    if (V == 2) {
        ushort2 o1; o1.x = f2bf(a1[0]); o1.y = f2bf(a1[1]);
        ushort2 o2; o2.x = f2bf(a2[0]); o2.y = f2bf(a2[1]);
        *(ushort2*)&D1[o] = o1;
        *(ushort2*)&D2[o] = o2;
    } else {
        D1[o] = f2bf(a1[0]);
        D2[o] = f2bf(a2[0]);
    }
}

template<int V>
__global__ __launch_bounds__(256) void k_spmm1(
    const unsigned short* __restrict__ S1, unsigned short* __restrict__ D1, int width,
    const int* __restrict__ base, const int* __restrict__ deg,
    const int* __restrict__ src, const float* __restrict__ w, int n)
{
    int node = blockIdx.x * 4 + threadIdx.y;
    if (node >= n) return;
    int tx = threadIdx.x;
    float a1[V];
    #pragma unroll
    for (int v = 0; v < V; v++) a1[v] = 0.f;
    int b = base[node], d = deg[node];
    for (int e = b; e < b + d; ++e) {
        int s = src[e];
        float we = w[e];
        const unsigned short* r1 = S1 + (size_t)s * width + tx * V;
        if (V == 2) {
            ushort2 x1 = *(const ushort2*)r1;
            a1[0] += we * bf2f(x1.x); a1[1] += we * bf2f(x1.y);
        } else {
            a1[0] += we * bf2f(*r1);
        }
    }
    size_t o = (size_t)node * width + tx * V;
    if (V == 2) {
        ushort2 o1; o1.x = f2bf(a1[0]); o1.y = f2bf(a1[1]);
        *(ushort2*)&D1[o] = o1;
    } else {
        D1[o] = f2bf(a1[0]);
    }
}

// ---------------------------------------------------------------------------
// BatchNorm (training batch stats) over concat of 3 bf16 N x 128 pieces.
// blockDim = 384. Apply is in-place + ReLU.
// ---------------------------------------------------------------------------
__global__ void k_bnstats(const unsigned short* __restrict__ p0,
                          const unsigned short* __restrict__ p1,
                          const unsigned short* __restrict__ p2,
                          float* __restrict__ sums, float* __restrict__ sumsq, int n)
{
    int c = threadIdx.x;
    int cc = c & 127;
    int pi = c >> 7;
    const unsigned short* src = (pi == 0) ? p0 : ((pi == 1) ? p1 : p2);
    float s = 0.f, s2 = 0.f;
    for (int r = blockIdx.x; r < n; r += gridDim.x) {
        float v = bf2f(src[(size_t)r * 128 + cc]);
        s += v; s2 += v * v;
    }
    atomicAdd(&sums[c], s);
    atomicAdd(&sumsq[c], s2);
}

__global__ void k_bnfin(const float* __restrict__ sums, const float* __restrict__ sumsq,
                        const float* __restrict__ g, const float* __restrict__ bb,
                        float* __restrict__ scale, float* __restrict__ shift,
                        int cat, float invn)
{
    int c = threadIdx.x;
    if (c >= cat) return;
    float mu  = sums[c] * invn;
    float var = sumsq[c] * invn - mu * mu;
    float sc  = g[c] * rsqrtf(var + 1e-5f);
    scale[c] = sc;
    shift[c] = bb[c] - mu * sc;
}

__global__ void k_bnapply(unsigned short* __restrict__ p0, unsigned short* __restrict__ p1,
                          unsigned short* __restrict__ p2,
                          const float* __restrict__ scale, const float* __restrict__ shift,
                          int n)
{
    int c = threadIdx.x;              // 384
    int cc = c & 127;
    int pi = c >> 7;
    unsigned short* src = (pi == 0) ? p0 : ((pi == 1) ? p1 : p2);
    float sc = scale[c], sh = shift[c];
    for (int r = blockIdx.x; r < n; r += gridDim.x) {
        size_t idx = (size_t)r * 128 + cc;
        float v = bf2f(src[idx]) * sc + sh;
        src[idx] = f2bf(fmaxf(v, 0.0f));
    }
}

// Diagnostic: if workspace is too small, surface ws_size (MB) via d_out.
__global__ void k_diag(float* out, float val, int n) {
    int i = blockIdx.x * blockDim.x + threadIdx.x;
    if (i < n) out[i] = val;
}

// ---------------------------------------------------------------------------
extern "C" void kernel_launch(void* const* d_in, const int* in_sizes, int n_in,
                              void* d_out, int out_size, void* d_ws, size_t ws_size,
                              hipStream_t stream)
{
    const float* x    = (const float*)d_in[0];
    const void*  ei   = d_in[1];
    const float* W0   = (const float*)d_in[2];
    const float* b0   = (const float*)d_in[3];
    const float* W1   = (const float*)d_in[4];
    const float* b1   = (const float*)d_in[5];
    const float* W2   = (const float*)d_in[6];
    const float* b2   = (const float*)d_in[7];
    const float* bn0g = (const float*)d_in[8];
    const float* bn0b = (const float*)d_in[9];
    const float* bn1g = (const float*)d_in[10];
    const float* bn1b = (const float*)d_in[11];
    const float* fpW  = (const float*)d_in[12];
    const float* fpb  = (const float*)d_in[13];
    float* out = (float*)d_out;

    const int N    = in_sizes[0] / IN_C;
    const int twoE = in_sizes[1];
    const int E    = twoE / 2;

    // ---- workspace carve (~181 MB; budget 256 MiB) ----
    char* p = (char*)d_ws;
    auto alloc = [&](size_t bytes) -> char* {
        char* r = p; p += (bytes + 255) & ~(size_t)255; return r;
    };
    unsigned short* U[6];
    for (int i = 0; i < 6; i++) U[i] = (unsigned short*)alloc((size_t)N * 128 * 2);
    float* dinv  = (float*)alloc((size_t)N * 4);
    float* csrw  = (float*)alloc((size_t)E * 4);
    float* sums  = (float*)alloc(2 * 384 * 4);
    float* sumsq = sums + 384;
    float* scale = (float*)alloc(384 * 4);
    float* shift = (float*)alloc(384 * 4);
    int* deg     = (int*)alloc((size_t)N * 4);
    int* base    = (int*)alloc((size_t)N * 4);
    int* cursor  = (int*)alloc((size_t)N * 4);
    int* csrsrc  = (int*)alloc((size_t)E * 4);
    int* eint    = (int*)alloc((size_t)twoE * 4);
    int* counter = (int*)alloc(4);
    int* flag    = (int*)alloc(4);

    size_t required = (size_t)(p - (char*)d_ws);
    if (required > ws_size) {
        k_diag<<<(out_size + 255) / 256, 256, 0, stream>>>(
            out, (float)(ws_size >> 20), out_size);
        return;
    }

    const int T = 256;
    dim3 spmm_blk(64, 4);
    int  spmm_grid = (N + 3) / 4;
    int  gx = (N + 63) / 64;

    // ---- graph build ----
    hipMemsetAsync(deg, 0, (size_t)N * 4, stream);
    hipMemsetAsync(counter, 0, 4, stream);
    k_detect<<<1, 64, 0, stream>>>((const long long*)ei, N, flag);
    k_cvt_edges<<<(twoE + T - 1) / T, T, 0, stream>>>(ei, twoE, flag, eint);
    k_hist<<<(E + T - 1) / T, T, 0, stream>>>(eint, E, deg, N);
    k_dinv<<<(N + T - 1) / T, T, 0, stream>>>(deg, dinv, N);
    k_alloc<<<(N + T - 1) / T, T, 0, stream>>>(deg, base, cursor, counter, N);
    k_scatter<<<(E + T - 1) / T, T, 0, stream>>>(eint, E, dinv, N, cursor, csrsrc, csrw);

    // ---- layer 0: x (fp32, read directly) -> G0:U0, G1:U1, G2:U2 (bf16) ----
    for (int j = 0; j < 3; j++)
        k_gemm64p<true><<<dim3(gx, 2), T, 0, stream>>>(x, x, x, IN_C, N,
            W0 + (size_t)j * IN_C * HIDc, HIDc, IN_C, b0 + j * HIDc, U[j], 128);
    // H1 = A*G1 -> U4 ; T = A*G2 -> U5 ; H2 = A*T -> U3
    k_spmm2<2><<<spmm_grid, spmm_blk, 0, stream>>>(U[1], U[2], U[4], U[5], 128,
                                                   base, deg, csrsrc, csrw, N);
    k_spmm1<2><<<spmm_grid, spmm_blk, 0, stream>>>(U[5], U[3], 128,
                                                   base, deg, csrsrc, csrw, N);
    hipMemsetAsync(sums, 0, 2 * 384 * 4, stream);
    k_bnstats<<<2048, 384, 0, stream>>>(U[0], U[4], U[3], sums, sumsq, N);
    k_bnfin<<<1, 384, 0, stream>>>(sums, sumsq, bn0g, bn0b, scale, shift, 384, 1.0f / N);
    k_bnapply<<<2048, 384, 0, stream>>>(U[0], U[4], U[3], scale, shift, N);
    // layer-0 output: (U0, U4, U3)

    // ---- layer 1: (U0,U4,U3) -> G0:U1, G1:U2, G2:U5 ----
    {
        unsigned short* o[3] = { U[1], U[2], U[5] };
        for (int j = 0; j < 3; j++)
            k_gemm64p_bf<true><<<dim3(gx, 2), T, 0, stream>>>(U[0], U[4], U[3], 128, N,
                W1 + (size_t)j * 384 * HIDc, HIDc, 384, b1 + j * HIDc, o[j], 128);
    }
    // H1 = A*G1 -> U0 ; T = A*G2 -> U4 ; H2 = A*T -> U3
    k_spmm2<2><<<spmm_grid, spmm_blk, 0, stream>>>(U[2], U[5], U[0], U[4], 128,
                                                   base, deg, csrsrc, csrw, N);
    k_spmm1<2><<<spmm_grid, spmm_blk, 0, stream>>>(U[4], U[3], 128,
                                                   base, deg, csrsrc, csrw, N);
    hipMemsetAsync(sums, 0, 2 * 384 * 4, stream);
    k_bnstats<<<2048, 384, 0, stream>>>(U[1], U[0], U[3], sums, sumsq, N);
    k_bnfin<<<1, 384, 0, stream>>>(sums, sumsq, bn1g, bn1b, scale, shift, 384, 1.0f / N);
    k_bnapply<<<2048, 384, 0, stream>>>(U[1], U[0], U[3], scale, shift, N);
    // layer-1 output: (U1, U0, U3)

    // ---- layer 2: (U1,U0,U3) -> 64-wide bf16 pieces in halves of U2/U4/U5 ----
    unsigned short* V2a = U[2];
    unsigned short* V2b = U[2] + (size_t)N * 64;
    unsigned short* V4a = U[4];
    unsigned short* V4b = U[4] + (size_t)N * 64;
    unsigned short* V5a = U[5];
    unsigned short* V5b = U[5] + (size_t)N * 64;
    {
        unsigned short* o[3] = { V2a, V2b, V4a };
        for (int j = 0; j < 3; j++)
            k_gemm64p_bf<true><<<dim3(gx, 1), T, 0, stream>>>(U[1], U[0], U[3], 128, N,
                W2 + (size_t)j * 384 * OUTc, OUTc, 384, b2 + j * OUTc, o[j], 64);
    }
    // A*G1 -> V4b(H1) ; T = A*G2 -> V5a ; A*T -> V5b(H2)
    k_spmm2<1><<<spmm_grid, spmm_blk, 0, stream>>>(V2b, V4a, V4b, V5a, 64,
                                                   base, deg, csrsrc, csrw, N);
    k_spmm1<1><<<spmm_grid, spmm_blk, 0, stream>>>(V5a, V5b, 64,
                                                   base, deg, csrsrc, csrw, N);

    // ---- final projection: out = concat(V2a, V4b, V5b)(N x 192) @ fpW + fpb ----
    k_gemm64p_bf<false><<<dim3(gx, 1), T, 0, stream>>>(V2a, V4b, V5b, OUTc, N,
        fpW, OUTc, 192, fpb, out, 64);
}

// Round 7
// 1419.663 us; speedup vs baseline: 1.9500x; 1.6112x over previous
//
#include <hip/hip_runtime.h>
#include <cstdint>
#include <cstddef>

#define IN_C 128
#define HIDc 128
#define OUTc 64

using bf8 = __attribute__((ext_vector_type(8))) __bf16;
using f4  = __attribute__((ext_vector_type(4))) float;

// ---- bf16 helpers (RNE) ----
__device__ __forceinline__ unsigned short f2bf(float f) {
    unsigned int u = __float_as_uint(f);
    unsigned int r = (u + 0x7FFFu + ((u >> 16) & 1u)) >> 16;
    return (unsigned short)r;
}
__device__ __forceinline__ float bf2f(unsigned short h) {
    return __uint_as_float(((unsigned int)h) << 16);
}

// ---------------------------------------------------------------------------
// MFMA layout probe (verified PASSING on HW in round 6 — retained as gate).
//   A: lane holds A[m=lane&15][k=(lane>>4)*8 + j]
//   B: lane holds B[k=(lane>>4)*8 + j][n=lane&15]
//   D: reg r holds D[row=(lane>>4)*4 + r][col=lane&15]
// ---------------------------------------------------------------------------
__device__ __forceinline__ float probeA(int m, int k) { return (float)((m * 7 + k * 3) % 13 - 6); }
__device__ __forceinline__ float probeB(int k, int n) { return (float)((k * 5 + n * 11) % 17 - 8); }

__global__ void k_probe(int* ok) {
    int lane = threadIdx.x;             // blockDim = 64
    int m16 = lane & 15, q = lane >> 4;
    bf8 a, b;
    #pragma unroll
    for (int j = 0; j < 8; j++) {
        a[j] = (__bf16)probeA(m16, q * 8 + j);
        b[j] = (__bf16)probeB(q * 8 + j, m16);
    }
    f4 acc = {0.f, 0.f, 0.f, 0.f};
    acc = __builtin_amdgcn_mfma_f32_16x16x32_bf16(a, b, acc, 0, 0, 0);
    int good = 1;
    #pragma unroll
    for (int r = 0; r < 4; r++) {
        int row = q * 4 + r, col = m16;
        float exp = 0.f;
        for (int k = 0; k < 32; k++) exp += probeA(row, k) * probeB(k, col);
        if (acc[r] != exp) good = 0;
    }
    unsigned long long m = __ballot(good);
    if (lane == 0) *ok = (m == ~0ull) ? 1 : 0;
}

// ---------------------------------------------------------------------------
// Edge dtype detection, conversion, graph build (battle-tested).
// ---------------------------------------------------------------------------
__global__ void k_detect(const long long* ei, int n_nodes, int* flag) {
    int t = threadIdx.x;                    // blockDim = 64
    long long v = ei[t];
    int ok = (v >= 0 && v < (long long)n_nodes) ? 1 : 0;
    unsigned long long m = __ballot(ok);
    if (t == 0) *flag = (m == ~0ull) ? 1 : 0;
}

__global__ void k_cvt_edges(const void* ei, int twoE, const int* flag, int* out) {
    int i = blockIdx.x * blockDim.x + threadIdx.x;
    if (i >= twoE) return;
    if (*flag) out[i] = (int)((const long long*)ei)[i];
    else       out[i] = ((const int*)ei)[i];
}

__global__ void k_hist(const int* __restrict__ eint, int E, int* __restrict__ deg, int n) {
    int e = blockIdx.x * blockDim.x + threadIdx.x;
    if (e >= E) return;
    int c = eint[E + e];
    if ((unsigned)c < (unsigned)n) atomicAdd(&deg[c], 1);
}

__global__ void k_dinv(const int* __restrict__ deg, float* __restrict__ dinv, int n) {
    int i = blockIdx.x * blockDim.x + threadIdx.x;
    if (i < n) dinv[i] = (deg[i] > 0) ? rsqrtf((float)deg[i]) : 0.0f;
}

__global__ void k_alloc(const int* __restrict__ deg, int* __restrict__ base,
                        int* __restrict__ cursor, int* __restrict__ counter, int n) {
    int i = blockIdx.x * blockDim.x + threadIdx.x;
    int lane = threadIdx.x & 63;
    int val = (i < n) ? deg[i] : 0;
    int scan = val;
    #pragma unroll
    for (int off = 1; off < 64; off <<= 1) {
        int t = __shfl_up(scan, off);
        if (lane >= off) scan += t;
    }
    int excl = scan - val;
    int total = __shfl(scan, 63);
    int wb = 0;
    if (lane == 0) wb = atomicAdd(counter, total);
    wb = __shfl(wb, 0);
    if (i < n) { base[i] = wb + excl; cursor[i] = wb + excl; }
}

__global__ void k_scatter(const int* __restrict__ eint, int E,
                          const float* __restrict__ dinv, int n,
                          int* __restrict__ cursor,
                          int* __restrict__ csr_src, float* __restrict__ csr_w) {
    int e = blockIdx.x * blockDim.x + threadIdx.x;
    if (e >= E) return;
    int r = eint[e];
    int c = eint[E + e];
    if ((unsigned)r >= (unsigned)n || (unsigned)c >= (unsigned)n) return;
    int p = atomicAdd(&cursor[c], 1);
    csr_src[p] = r;
    csr_w[p]   = dinv[r] * dinv[c];
}

// ---------------------------------------------------------------------------
// Weight prep: W (nstack, K, N) fp32 -> Wt (nstack, N, K) bf16.
// ---------------------------------------------------------------------------
__global__ void k_wprep(const float* __restrict__ W, unsigned short* __restrict__ Wt,
                        int K, int N) {
    int j = blockIdx.y;
    int idx = blockIdx.x * 256 + threadIdx.x;
    if (idx >= K * N) return;
    int k = idx / N, nn = idx - k * N;
    Wt[(size_t)j * N * K + (size_t)nn * K + k] = f2bf(W[(size_t)j * K * N + idx]);
}

__global__ void k_cast4(const float* __restrict__ x, unsigned short* __restrict__ y, int n4) {
    int i = blockIdx.x * 256 + threadIdx.x;
    if (i >= n4) return;
    float4 v = ((const float4*)x)[i];
    ushort4 o;
    o.x = f2bf(v.x); o.y = f2bf(v.y); o.z = f2bf(v.z); o.w = f2bf(v.w);
    ((ushort4*)y)[i] = o;
}

// ---------------------------------------------------------------------------
// VALU GEMM fallback (runs only if MFMA probe FAILED).
// ---------------------------------------------------------------------------
template<bool BFOUT>
__global__ __launch_bounds__(256) void k_gemm64p(
    const int* __restrict__ ok,
    const float* __restrict__ A0, const float* __restrict__ A1,
    const float* __restrict__ A2, int W, int M,
    const float* __restrict__ B, int ldb, int K,
    const float* __restrict__ bias,
    void* __restrict__ Cv, int ldc)
{
    if (ok[0] != 0) return;
    __shared__ __align__(16) float As[16][64];
    __shared__ __align__(16) float Bs[16][64];
    int t  = threadIdx.x;
    int tx = t & 15, ty = t >> 4;
    int row0 = blockIdx.x * 64, col0 = blockIdx.y * 64;
    float acc[4][4] = {{0.f}};
    int am = t >> 2;
    int ak = (t & 3) * 4;
    int bk = t >> 4;
    int bc = (t & 15) * 4;

    for (int k0 = 0; k0 < K; k0 += 16) {
        int pi = k0 / W;
        const float* Ap = (pi == 0) ? A0 : ((pi == 1) ? A1 : A2);
        int kl = k0 - pi * W;
        int arow = row0 + am; if (arow >= M) arow = M - 1;
        float4 a  = *(const float4*)&Ap[(size_t)arow * W + kl + ak];
        float4 bv = *(const float4*)&B[(size_t)(k0 + bk) * ldb + col0 + bc];
        __syncthreads();
        As[ak + 0][am] = a.x; As[ak + 1][am] = a.y;
        As[ak + 2][am] = a.z; As[ak + 3][am] = a.w;
        *(float4*)&Bs[bk][bc] = bv;
        __syncthreads();
        #pragma unroll
        for (int k = 0; k < 16; k++) {
            float av[4], bw[4];
            *(float4*)av = *(const float4*)&As[k][ty * 4];
            *(float4*)bw = *(const float4*)&Bs[k][tx * 4];
            #pragma unroll
            for (int i = 0; i < 4; i++)
                #pragma unroll
                for (int j = 0; j < 4; j++)
                    acc[i][j] += av[i] * bw[j];
        }
    }
    #pragma unroll
    for (int i = 0; i < 4; i++) {
        int r = row0 + ty * 4 + i;
        if (r >= M) continue;
        #pragma unroll
        for (int j = 0; j < 4; j++) {
            int c = col0 + tx * 4 + j;
            float v = acc[i][j] + bias[c];
            if (BFOUT) ((unsigned short*)Cv)[(size_t)r * ldc + c] = f2bf(v);
            else       ((float*)Cv)[(size_t)r * ldc + c] = v;
        }
    }
}

template<bool BFOUT>
__global__ __launch_bounds__(256) void k_gemm64p_bf(
    const int* __restrict__ ok,
    const unsigned short* __restrict__ A0, const unsigned short* __restrict__ A1,
    const unsigned short* __restrict__ A2, int W, int M,
    const float* __restrict__ B, int ldb, int K,
    const float* __restrict__ bias,
    void* __restrict__ Cv, int ldc)
{
    if (ok[0] != 0) return;
    __shared__ __align__(16) float As[16][64];
    __shared__ __align__(16) float Bs[16][64];
    int t  = threadIdx.x;
    int tx = t & 15, ty = t >> 4;
    int row0 = blockIdx.x * 64, col0 = blockIdx.y * 64;
    float acc[4][4] = {{0.f}};
    int am = t >> 2;
    int ak = (t & 3) * 4;
    int bk = t >> 4;
    int bc = (t & 15) * 4;

    for (int k0 = 0; k0 < K; k0 += 16) {
        int pi = k0 / W;
        const unsigned short* Ap = (pi == 0) ? A0 : ((pi == 1) ? A1 : A2);
        int kl = k0 - pi * W;
        int arow = row0 + am; if (arow >= M) arow = M - 1;
        ushort4 a4 = *(const ushort4*)&Ap[(size_t)arow * W + kl + ak];
        float4 bv = *(const float4*)&B[(size_t)(k0 + bk) * ldb + col0 + bc];
        __syncthreads();
        As[ak + 0][am] = bf2f(a4.x); As[ak + 1][am] = bf2f(a4.y);
        As[ak + 2][am] = bf2f(a4.z); As[ak + 3][am] = bf2f(a4.w);
        *(float4*)&Bs[bk][bc] = bv;
        __syncthreads();
        #pragma unroll
        for (int k = 0; k < 16; k++) {
            float av[4], bw[4];
            *(float4*)av = *(const float4*)&As[k][ty * 4];
            *(float4*)bw = *(const float4*)&Bs[k][tx * 4];
            #pragma unroll
            for (int i = 0; i < 4; i++)
                #pragma unroll
                for (int j = 0; j < 4; j++)
                    acc[i][j] += av[i] * bw[j];
        }
    }
    #pragma unroll
    for (int i = 0; i < 4; i++) {
        int r = row0 + ty * 4 + i;
        if (r >= M) continue;
        #pragma unroll
        for (int j = 0; j < 4; j++) {
            int c = col0 + tx * 4 + j;
            float v = acc[i][j] + bias[c];
            if (BFOUT) ((unsigned short*)Cv)[(size_t)r * ldc + c] = f2bf(v);
            else       ((float*)Cv)[(size_t)r * ldc + c] = v;
        }
    }
}

// ---------------------------------------------------------------------------
// MFMA bf16 GEMM (runs only if probe PASSED).
// C(M x BN) = concat(A0,A1,A2)(M x K, piece width W bf16) @ Bt^T + bias,
// Bt is (BN x K) bf16. Block tile 128 x BN, 4 waves, BK=32.
// FIX vs round 4/6: Bt is indexed by GLOBAL k (kk), not piece-local kl.
// (kl applies only to the piecewise A tensor; using kl for B silently read
//  B[k mod 128] for K=384 layers -> the deterministic absmax 6.39.)
// ---------------------------------------------------------------------------
template<int BN, bool BF16OUT>
__global__ __launch_bounds__(256) void k_mfma(
    const int* __restrict__ ok,
    const unsigned short* __restrict__ A0, const unsigned short* __restrict__ A1,
    const unsigned short* __restrict__ A2, int W, int M, int K,
    const unsigned short* __restrict__ Bt, const float* __restrict__ bias,
    void* __restrict__ Cv, int ldc)
{
    if (ok[0] == 0) return;
    constexpr int TM = (BN == 128) ? 4 : 2;
    constexpr int TN = 4;
    __shared__ __align__(16) unsigned short As[128 * 40];  // +8 pad: 2-way banks (free)
    __shared__ __align__(16) unsigned short Bs[BN * 40];

    int t = threadIdx.x;
    int wave = t >> 6, lane = t & 63;
    int m16 = lane & 15, q = lane >> 4;
    int row0 = blockIdx.x * 128;
    int wr = (BN == 128) ? (wave & 1) * 64 : wave * 32;
    int wc = (BN == 128) ? (wave >> 1) * 64 : 0;

    f4 acc[TM][TN];
    #pragma unroll
    for (int i = 0; i < TM; i++)
        #pragma unroll
        for (int j = 0; j < TN; j++) acc[i][j] = (f4){0.f, 0.f, 0.f, 0.f};

    int ar = t & 127, ah = t >> 7;          // A staging: 128 rows x 2 halves(16 cols)

    for (int kk = 0; kk < K; kk += 32) {
        int pi = kk / W;
        const unsigned short* Ap = (pi == 0) ? A0 : ((pi == 1) ? A1 : A2);
        int kl = kk - pi * W;               // piece-local offset: A ONLY

        int arow = row0 + ar; if (arow >= M) arow = M - 1;
        const uint4* asrc = (const uint4*)&Ap[(size_t)arow * W + kl + ah * 16];
        uint4 av0 = asrc[0], av1 = asrc[1];
        uint4 bv0, bv1;
        if (BN == 128) {
            const uint4* bsrc = (const uint4*)&Bt[(size_t)(t & 127) * K + kk + ah * 16];
            bv0 = bsrc[0]; bv1 = bsrc[1];
        } else {
            const uint4* bsrc = (const uint4*)&Bt[(size_t)(t & 63) * K + kk + (t >> 6) * 8];
            bv0 = bsrc[0];
        }
        __syncthreads();
        *(uint4*)&As[ar * 40 + ah * 16]     = av0;
        *(uint4*)&As[ar * 40 + ah * 16 + 8] = av1;
        if (BN == 128) {
            *(uint4*)&Bs[(t & 127) * 40 + ah * 16]     = bv0;
            *(uint4*)&Bs[(t & 127) * 40 + ah * 16 + 8] = bv1;
        } else {
            *(uint4*)&Bs[(t & 63) * 40 + (t >> 6) * 8] = bv0;
        }
        __syncthreads();

        bf8 af[TM], bfr[TN];
        #pragma unroll
        for (int tm = 0; tm < TM; tm++)
            af[tm] = *(const bf8*)&As[(wr + tm * 16 + m16) * 40 + q * 8];
        #pragma unroll
        for (int tn = 0; tn < TN; tn++)
            bfr[tn] = *(const bf8*)&Bs[(wc + tn * 16 + m16) * 40 + q * 8];
        #pragma unroll
        for (int tm = 0; tm < TM; tm++)
            #pragma unroll
            for (int tn = 0; tn < TN; tn++)
                acc[tm][tn] = __builtin_amdgcn_mfma_f32_16x16x32_bf16(
                    af[tm], bfr[tn], acc[tm][tn], 0, 0, 0);
    }

    #pragma unroll
    for (int tm = 0; tm < TM; tm++) {
        #pragma unroll
        for (int tn = 0; tn < TN; tn++) {
            int col = wc + tn * 16 + m16;
            float bi = bias[col];
            #pragma unroll
            for (int r = 0; r < 4; r++) {
                int row = row0 + wr + tm * 16 + q * 4 + r;
                if (row >= M) continue;
                float v = acc[tm][tn][r] + bi;
                if (BF16OUT)
                    ((unsigned short*)Cv)[(size_t)row * ldc + col] = f2bf(v);
                else
                    ((float*)Cv)[(size_t)row * ldc + col] = v;
            }
        }
    }
}

// ---------------------------------------------------------------------------
// SpMM (bf16 in/out, fp32 accumulate), unroll-by-4. One wave per node.
// ---------------------------------------------------------------------------
template<int V>
__global__ __launch_bounds__(256) void k_spmm2(
    const unsigned short* __restrict__ S1, const unsigned short* __restrict__ S2,
    unsigned short* __restrict__ D1, unsigned short* __restrict__ D2, int width,
    const int* __restrict__ base, const int* __restrict__ deg,
    const int* __restrict__ src, const float* __restrict__ w, int n)
{
    int node = blockIdx.x * 4 + threadIdx.y;
    if (node >= n) return;
    int tx = threadIdx.x;
    float a1[V], a2[V];
    #pragma unroll
    for (int v = 0; v < V; v++) { a1[v] = 0.f; a2[v] = 0.f; }
    int b = base[node], end = b + deg[node];
    const unsigned short* P1 = S1 + tx * V;
    const unsigned short* P2 = S2 + tx * V;
    int e = b;
    for (; e + 4 <= end; e += 4) {
        int s0 = src[e + 0], s1 = src[e + 1], s2 = src[e + 2], s3 = src[e + 3];
        float w0 = w[e + 0], w1 = w[e + 1], w2 = w[e + 2], w3 = w[e + 3];
        if (V == 2) {
            ushort2 q10 = *(const ushort2*)(P1 + (size_t)s0 * width);
            ushort2 q11 = *(const ushort2*)(P1 + (size_t)s1 * width);
            ushort2 q12 = *(const ushort2*)(P1 + (size_t)s2 * width);
            ushort2 q13 = *(const ushort2*)(P1 + (size_t)s3 * width);
            ushort2 q20 = *(const ushort2*)(P2 + (size_t)s0 * width);
            ushort2 q21 = *(const ushort2*)(P2 + (size_t)s1 * width);
            ushort2 q22 = *(const ushort2*)(P2 + (size_t)s2 * width);
            ushort2 q23 = *(const ushort2*)(P2 + (size_t)s3 * width);
            a1[0] += w0 * bf2f(q10.x); a1[1] += w0 * bf2f(q10.y);
            a1[0] += w1 * bf2f(q11.x); a1[1] += w1 * bf2f(q11.y);
            a1[0] += w2 * bf2f(q12.x); a1[1] += w2 * bf2f(q12.y);
            a1[0] += w3 * bf2f(q13.x); a1[1] += w3 * bf2f(q13.y);
            a2[0] += w0 * bf2f(q20.x); a2[1] += w0 * bf2f(q20.y);
            a2[0] += w1 * bf2f(q21.x); a2[1] += w1 * bf2f(q21.y);
            a2[0] += w2 * bf2f(q22.x); a2[1] += w2 * bf2f(q22.y);
            a2[0] += w3 * bf2f(q23.x); a2[1] += w3 * bf2f(q23.y);
        } else {
            unsigned short q10 = P1[(size_t)s0 * width];
            unsigned short q11 = P1[(size_t)s1 * width];
            unsigned short q12 = P1[(size_t)s2 * width];
            unsigned short q13 = P1[(size_t)s3 * width];
            unsigned short q20 = P2[(size_t)s0 * width];
            unsigned short q21 = P2[(size_t)s1 * width];
            unsigned short q22 = P2[(size_t)s2 * width];
            unsigned short q23 = P2[(size_t)s3 * width];
            a1[0] += w0 * bf2f(q10) + w1 * bf2f(q11) + w2 * bf2f(q12) + w3 * bf2f(q13);
            a2[0] += w0 * bf2f(q20) + w1 * bf2f(q21) + w2 * bf2f(q22) + w3 * bf2f(q23);
        }
    }
    for (; e < end; ++e) {
        int s = src[e];
        float we = w[e];
        if (V == 2) {
            ushort2 x1 = *(const ushort2*)(P1 + (size_t)s * width);
            ushort2 x2 = *(const ushort2*)(P2 + (size_t)s * width);
            a1[0] += we * bf2f(x1.x); a1[1] += we * bf2f(x1.y);
            a2[0] += we * bf2f(x2.x); a2[1] += we * bf2f(x2.y);
        } else {
            a1[0] += we * bf2f(P1[(size_t)s * width]);
            a2[0] += we * bf2f(P2[(size_t)s * width]);
        }
    }
    size_t o = (size_t)node * width + tx * V;
    if (V == 2) {
        ushort2 o1; o1.x = f2bf(a1[0]); o1.y = f2bf(a1[1]);
        ushort2 o2; o2.x = f2bf(a2[0]); o2.y = f2bf(a2[1]);
        *(ushort2*)&D1[o] = o1;
        *(ushort2*)&D2[o] = o2;
    } else {
        D1[o] = f2bf(a1[0]);
        D2[o] = f2bf(a2[0]);
    }
}

template<int V>
__global__ __launch_bounds__(256) void k_spmm1(
    const unsigned short* __restrict__ S1, unsigned short* __restrict__ D1, int width,
    const int* __restrict__ base, const int* __restrict__ deg,
    const int* __restrict__ src, const float* __restrict__ w, int n)
{
    int node = blockIdx.x * 4 + threadIdx.y;
    if (node >= n) return;
    int tx = threadIdx.x;
    float a1[V];
    #pragma unroll
    for (int v = 0; v < V; v++) a1[v] = 0.f;
    int b = base[node], end = b + deg[node];
    const unsigned short* P1 = S1 + tx * V;
    int e = b;
    for (; e + 4 <= end; e += 4) {
        int s0 = src[e + 0], s1 = src[e + 1], s2 = src[e + 2], s3 = src[e + 3];
        float w0 = w[e + 0], w1 = w[e + 1], w2 = w[e + 2], w3 = w[e + 3];
        if (V == 2) {
            ushort2 q10 = *(const ushort2*)(P1 + (size_t)s0 * width);
            ushort2 q11 = *(const ushort2*)(P1 + (size_t)s1 * width);
            ushort2 q12 = *(const ushort2*)(P1 + (size_t)s2 * width);
            ushort2 q13 = *(const ushort2*)(P1 + (size_t)s3 * width);
            a1[0] += w0 * bf2f(q10.x); a1[1] += w0 * bf2f(q10.y);
            a1[0] += w1 * bf2f(q11.x); a1[1] += w1 * bf2f(q11.y);
            a1[0] += w2 * bf2f(q12.x); a1[1] += w2 * bf2f(q12.y);
            a1[0] += w3 * bf2f(q13.x); a1[1] += w3 * bf2f(q13.y);
        } else {
            unsigned short q10 = P1[(size_t)s0 * width];
            unsigned short q11 = P1[(size_t)s1 * width];
            unsigned short q12 = P1[(size_t)s2 * width];
            unsigned short q13 = P1[(size_t)s3 * width];
            a1[0] += w0 * bf2f(q10) + w1 * bf2f(q11) + w2 * bf2f(q12) + w3 * bf2f(q13);
        }
    }
    for (; e < end; ++e) {
        int s = src[e];
        float we = w[e];
        if (V == 2) {
            ushort2 x1 = *(const ushort2*)(P1 + (size_t)s * width);
            a1[0] += we * bf2f(x1.x); a1[1] += we * bf2f(x1.y);
        } else {
            a1[0] += we * bf2f(P1[(size_t)s * width]);
        }
    }
    size_t o = (size_t)node * width + tx * V;
    if (V == 2) {
        ushort2 o1; o1.x = f2bf(a1[0]); o1.y = f2bf(a1[1]);
        *(ushort2*)&D1[o] = o1;
    } else {
        D1[o] = f2bf(a1[0]);
    }
}

// ---------------------------------------------------------------------------
// BatchNorm (training batch stats) over concat of 3 bf16 N x 128 pieces.
// ---------------------------------------------------------------------------
__global__ void k_bnstats(const unsigned short* __restrict__ p0,
                          const unsigned short* __restrict__ p1,
                          const unsigned short* __restrict__ p2,
                          float* __restrict__ sums, float* __restrict__ sumsq, int n)
{
    int c = threadIdx.x;
    int cc = c & 127;
    int pi = c >> 7;
    const unsigned short* src = (pi == 0) ? p0 : ((pi == 1) ? p1 : p2);
    float s = 0.f, s2 = 0.f;
    for (int r = blockIdx.x; r < n; r += gridDim.x) {
        float v = bf2f(src[(size_t)r * 128 + cc]);
        s += v; s2 += v * v;
    }
    atomicAdd(&sums[c], s);
    atomicAdd(&sumsq[c], s2);
}

__global__ void k_bnfin(const float* __restrict__ sums, const float* __restrict__ sumsq,
                        const float* __restrict__ g, const float* __restrict__ bb,
                        float* __restrict__ scale, float* __restrict__ shift,
                        int cat, float invn)
{
    int c = threadIdx.x;
    if (c >= cat) return;
    float mu  = sums[c] * invn;
    float var = sumsq[c] * invn - mu * mu;
    float sc  = g[c] * rsqrtf(var + 1e-5f);
    scale[c] = sc;
    shift[c] = bb[c] - mu * sc;
}

__global__ void k_bnapply(unsigned short* __restrict__ p0, unsigned short* __restrict__ p1,
                          unsigned short* __restrict__ p2,
                          const float* __restrict__ scale, const float* __restrict__ shift,
                          int n)
{
    int c = threadIdx.x;              // 384
    int cc = c & 127;
    int pi = c >> 7;
    unsigned short* src = (pi == 0) ? p0 : ((pi == 1) ? p1 : p2);
    float sc = scale[c], sh = shift[c];
    for (int r = blockIdx.x; r < n; r += gridDim.x) {
        size_t idx = (size_t)r * 128 + cc;
        float v = bf2f(src[idx]) * sc + sh;
        src[idx] = f2bf(fmaxf(v, 0.0f));
    }
}

// Diagnostic: if workspace is too small, surface ws_size (MB) via d_out.
__global__ void k_diag(float* out, float val, int n) {
    int i = blockIdx.x * blockDim.x + threadIdx.x;
    if (i < n) out[i] = val;
}

// ---------------------------------------------------------------------------
extern "C" void kernel_launch(void* const* d_in, const int* in_sizes, int n_in,
                              void* d_out, int out_size, void* d_ws, size_t ws_size,
                              hipStream_t stream)
{
    const float* x    = (const float*)d_in[0];
    const void*  ei   = d_in[1];
    const float* W0   = (const float*)d_in[2];
    const float* b0   = (const float*)d_in[3];
    const float* W1   = (const float*)d_in[4];
    const float* b1   = (const float*)d_in[5];
    const float* W2   = (const float*)d_in[6];
    const float* b2   = (const float*)d_in[7];
    const float* bn0g = (const float*)d_in[8];
    const float* bn0b = (const float*)d_in[9];
    const float* bn1g = (const float*)d_in[10];
    const float* bn1b = (const float*)d_in[11];
    const float* fpW  = (const float*)d_in[12];
    const float* fpb  = (const float*)d_in[13];
    float* out = (float*)d_out;

    const int N    = in_sizes[0] / IN_C;
    const int twoE = in_sizes[1];
    const int E    = twoE / 2;

    // ---- workspace carve (~184 MB; budget 256 MiB) ----
    char* p = (char*)d_ws;
    auto alloc = [&](size_t bytes) -> char* {
        char* r = p; p += (bytes + 255) & ~(size_t)255; return r;
    };
    unsigned short* U[6];
    for (int i = 0; i < 6; i++) U[i] = (unsigned short*)alloc((size_t)N * 128 * 2);
    unsigned short* Wt0 = (unsigned short*)alloc((size_t)3 * 128 * 128 * 2);
    unsigned short* Wt1 = (unsigned short*)alloc((size_t)3 * 384 * 128 * 2);
    unsigned short* Wt2 = (unsigned short*)alloc((size_t)3 * 384 * 64 * 2);
    unsigned short* WtF = (unsigned short*)alloc((size_t)192 * 64 * 2);
    float* dinv  = (float*)alloc((size_t)N * 4);
    float* csrw  = (float*)alloc((size_t)E * 4);
    float* sums  = (float*)alloc(2 * 384 * 4);
    float* sumsq = sums + 384;
    float* scale = (float*)alloc(384 * 4);
    float* shift = (float*)alloc(384 * 4);
    int* deg     = (int*)alloc((size_t)N * 4);
    int* base    = (int*)alloc((size_t)N * 4);
    int* cursor  = (int*)alloc((size_t)N * 4);
    int* csrsrc  = (int*)alloc((size_t)E * 4);
    int* eint    = (int*)alloc((size_t)twoE * 4);
    int* counter = (int*)alloc(4);
    int* flag    = (int*)alloc(4);
    int* mok     = (int*)alloc(4);

    size_t required = (size_t)(p - (char*)d_ws);
    if (required > ws_size) {
        k_diag<<<(out_size + 255) / 256, 256, 0, stream>>>(
            out, (float)(ws_size >> 20), out_size);
        return;
    }

    const int T = 256;
    dim3 spmm_blk(64, 4);
    int  spmm_grid = (N + 3) / 4;
    int  gx64  = (N + 63) / 64;
    int  gx128 = (N + 127) / 128;

    // ---- MFMA layout probe ----
    k_probe<<<1, 64, 0, stream>>>(mok);

    // ---- weight prep + input cast ----
    k_wprep<<<dim3((128 * 128 + 255) / 256, 3), T, 0, stream>>>(W0, Wt0, 128, 128);
    k_wprep<<<dim3((384 * 128 + 255) / 256, 3), T, 0, stream>>>(W1, Wt1, 384, 128);
    k_wprep<<<dim3((384 * 64  + 255) / 256, 3), T, 0, stream>>>(W2, Wt2, 384, 64);
    k_wprep<<<dim3((192 * 64  + 255) / 256, 1), T, 0, stream>>>(fpW, WtF, 192, 64);
    unsigned short* Xb = U[3];
    k_cast4<<<((N * 128 / 4) + 255) / 256, T, 0, stream>>>(x, Xb, N * 128 / 4);

    // ---- graph build ----
    hipMemsetAsync(deg, 0, (size_t)N * 4, stream);
    hipMemsetAsync(counter, 0, 4, stream);
    k_detect<<<1, 64, 0, stream>>>((const long long*)ei, N, flag);
    k_cvt_edges<<<(twoE + T - 1) / T, T, 0, stream>>>(ei, twoE, flag, eint);
    k_hist<<<(E + T - 1) / T, T, 0, stream>>>(eint, E, deg, N);
    k_dinv<<<(N + T - 1) / T, T, 0, stream>>>(deg, dinv, N);
    k_alloc<<<(N + T - 1) / T, T, 0, stream>>>(deg, base, cursor, counter, N);
    k_scatter<<<(E + T - 1) / T, T, 0, stream>>>(eint, E, dinv, N, cursor, csrsrc, csrw);

    // ---- layer 0: x -> G0:U0, G1:U1, G2:U2 (bf16) ----
    for (int j = 0; j < 3; j++) {
        k_gemm64p<true><<<dim3(gx64, 2), T, 0, stream>>>(mok, x, x, x, IN_C, N,
            W0 + (size_t)j * IN_C * HIDc, HIDc, IN_C, b0 + j * HIDc, U[j], 128);
        k_mfma<128, true><<<gx128, T, 0, stream>>>(mok, Xb, Xb, Xb, 128, N, 128,
            Wt0 + (size_t)j * 128 * 128, b0 + j * HIDc, U[j], 128);
    }
    // H1 = A*G1 -> U4 ; T = A*G2 -> U5 ; H2 = A*T -> U3
    k_spmm2<2><<<spmm_grid, spmm_blk, 0, stream>>>(U[1], U[2], U[4], U[5], 128,
                                                   base, deg, csrsrc, csrw, N);
    k_spmm1<2><<<spmm_grid, spmm_blk, 0, stream>>>(U[5], U[3], 128,
                                                   base, deg, csrsrc, csrw, N);
    hipMemsetAsync(sums, 0, 2 * 384 * 4, stream);
    k_bnstats<<<2048, 384, 0, stream>>>(U[0], U[4], U[3], sums, sumsq, N);
    k_bnfin<<<1, 384, 0, stream>>>(sums, sumsq, bn0g, bn0b, scale, shift, 384, 1.0f / N);
    k_bnapply<<<2048, 384, 0, stream>>>(U[0], U[4], U[3], scale, shift, N);
    // layer-0 output: (U0, U4, U3)

    // ---- layer 1: (U0,U4,U3) -> G0:U1, G1:U2, G2:U5 ----
    {
        unsigned short* o[3] = { U[1], U[2], U[5] };
        for (int j = 0; j < 3; j++) {
            k_gemm64p_bf<true><<<dim3(gx64, 2), T, 0, stream>>>(mok, U[0], U[4], U[3], 128, N,
                W1 + (size_t)j * 384 * HIDc, HIDc, 384, b1 + j * HIDc, o[j], 128);
            k_mfma<128, true><<<gx128, T, 0, stream>>>(mok, U[0], U[4], U[3], 128, N, 384,
                Wt1 + (size_t)j * 128 * 384, b1 + j * HIDc, o[j], 128);
        }
    }
    // H1 = A*G1 -> U0 ; T = A*G2 -> U4 ; H2 = A*T -> U3
    k_spmm2<2><<<spmm_grid, spmm_blk, 0, stream>>>(U[2], U[5], U[0], U[4], 128,
                                                   base, deg, csrsrc, csrw, N);
    k_spmm1<2><<<spmm_grid, spmm_blk, 0, stream>>>(U[4], U[3], 128,
                                                   base, deg, csrsrc, csrw, N);
    hipMemsetAsync(sums, 0, 2 * 384 * 4, stream);
    k_bnstats<<<2048, 384, 0, stream>>>(U[1], U[0], U[3], sums, sumsq, N);
    k_bnfin<<<1, 384, 0, stream>>>(sums, sumsq, bn1g, bn1b, scale, shift, 384, 1.0f / N);
    k_bnapply<<<2048, 384, 0, stream>>>(U[1], U[0], U[3], scale, shift, N);
    // layer-1 output: (U1, U0, U3)

    // ---- layer 2: (U1,U0,U3) -> 64-wide bf16 pieces in halves of U2/U4/U5 ----
    unsigned short* V2a = U[2];
    unsigned short* V2b = U[2] + (size_t)N * 64;
    unsigned short* V4a = U[4];
    unsigned short* V4b = U[4] + (size_t)N * 64;
    unsigned short* V5a = U[5];
    unsigned short* V5b = U[5] + (size_t)N * 64;
    {
        unsigned short* o[3] = { V2a, V2b, V4a };
        for (int j = 0; j < 3; j++) {
            k_gemm64p_bf<true><<<dim3(gx64, 1), T, 0, stream>>>(mok, U[1], U[0], U[3], 128, N,
                W2 + (size_t)j * 384 * OUTc, OUTc, 384, b2 + j * OUTc, o[j], 64);
            k_mfma<64, true><<<gx128, T, 0, stream>>>(mok, U[1], U[0], U[3], 128, N, 384,
                Wt2 + (size_t)j * 64 * 384, b2 + j * OUTc, o[j], 64);
        }
    }
    // A*G1 -> V4b(H1) ; T = A*G2 -> V5a ; A*T -> V5b(H2)
    k_spmm2<1><<<spmm_grid, spmm_blk, 0, stream>>>(V2b, V4a, V4b, V5a, 64,
                                                   base, deg, csrsrc, csrw, N);
    k_spmm1<1><<<spmm_grid, spmm_blk, 0, stream>>>(V5a, V5b, 64,
                                                   base, deg, csrsrc, csrw, N);

    // ---- final projection: out = concat(V2a, V4b, V5b)(N x 192) @ fpW + fpb ----
    k_gemm64p_bf<false><<<dim3(gx64, 1), T, 0, stream>>>(mok, V2a, V4b, V5b, OUTc, N,
        fpW, OUTc, 192, fpb, out, 64);
    k_mfma<64, false><<<gx128, T, 0, stream>>>(mok, V2a, V4b, V5b, 64, N, 192,
        WtF, fpb, out, 64);
}

// Round 8
// 1370.533 us; speedup vs baseline: 2.0199x; 1.0358x over previous
//
#include <hip/hip_runtime.h>
#include <cstdint>
#include <cstddef>

#define IN_C 128
#define HIDc 128
#define OUTc 64

using bf8 = __attribute__((ext_vector_type(8))) __bf16;
using f4  = __attribute__((ext_vector_type(4))) float;

// ---- bf16 helpers (RNE) ----
__device__ __forceinline__ unsigned short f2bf(float f) {
    unsigned int u = __float_as_uint(f);
    unsigned int r = (u + 0x7FFFu + ((u >> 16) & 1u)) >> 16;
    return (unsigned short)r;
}
__device__ __forceinline__ float bf2f(unsigned short h) {
    return __uint_as_float(((unsigned int)h) << 16);
}

// ---------------------------------------------------------------------------
// Graph build. Edge dtype detect (int64 vs int32 storage) is battle-tested.
// ---------------------------------------------------------------------------
__global__ void k_detect(const long long* ei, int n_nodes, int* flag) {
    int t = threadIdx.x;                    // blockDim = 64
    long long v = ei[t];
    int ok = (v >= 0 && v < (long long)n_nodes) ? 1 : 0;
    unsigned long long m = __ballot(ok);
    if (t == 0) *flag = (m == ~0ull) ? 1 : 0;
}

// Convert edges AND histogram destinations in one pass.
__global__ void k_cvt_hist(const void* ei, int twoE, int E, const int* flag,
                           int* __restrict__ out, int* __restrict__ deg, int n) {
    int i = blockIdx.x * blockDim.x + threadIdx.x;
    if (i >= twoE) return;
    int v = (*flag) ? (int)((const long long*)ei)[i] : ((const int*)ei)[i];
    out[i] = v;
    if (i >= E && (unsigned)v < (unsigned)n) atomicAdd(&deg[v], 1);
}

__global__ void k_dinv(const int* __restrict__ deg, float* __restrict__ dinv, int n) {
    int i = blockIdx.x * blockDim.x + threadIdx.x;
    if (i < n) dinv[i] = (deg[i] > 0) ? rsqrtf((float)deg[i]) : 0.0f;
}

__global__ void k_alloc(const int* __restrict__ deg, int* __restrict__ base,
                        int* __restrict__ cursor, int* __restrict__ counter, int n) {
    int i = blockIdx.x * blockDim.x + threadIdx.x;
    int lane = threadIdx.x & 63;
    int val = (i < n) ? deg[i] : 0;
    int scan = val;
    #pragma unroll
    for (int off = 1; off < 64; off <<= 1) {
        int t = __shfl_up(scan, off);
        if (lane >= off) scan += t;
    }
    int excl = scan - val;
    int total = __shfl(scan, 63);
    int wb = 0;
    if (lane == 0) wb = atomicAdd(counter, total);
    wb = __shfl(wb, 0);
    if (i < n) { base[i] = wb + excl; cursor[i] = wb + excl; }
}

// Packed payload: one 8B store per edge (int src | float weight) — halves the
// random-write cache-line amplification vs two 4B arrays (r7: WRITE 155 MB).
__global__ void k_scatter(const int* __restrict__ eint, int E,
                          const float* __restrict__ dinv, int n,
                          int* __restrict__ cursor, int2* __restrict__ ew) {
    int e = blockIdx.x * blockDim.x + threadIdx.x;
    if (e >= E) return;
    int r = eint[e];
    int c = eint[E + e];
    if ((unsigned)r >= (unsigned)n || (unsigned)c >= (unsigned)n) return;
    int p = atomicAdd(&cursor[c], 1);
    int2 v; v.x = r; v.y = __float_as_int(dinv[r] * dinv[c]);
    ew[p] = v;
}

// ---------------------------------------------------------------------------
// Weight prep: W (nstack, K, N) fp32 -> Wt (nstack*N rows, K) bf16 (transposed).
// ---------------------------------------------------------------------------
__global__ void k_wprep(const float* __restrict__ W, unsigned short* __restrict__ Wt,
                        int K, int N) {
    int j = blockIdx.y;
    int idx = blockIdx.x * 256 + threadIdx.x;
    if (idx >= K * N) return;
    int k = idx / N, nn = idx - k * N;
    Wt[(size_t)j * N * K + (size_t)nn * K + k] = f2bf(W[(size_t)j * K * N + idx]);
}

__global__ void k_cast4(const float* __restrict__ x, unsigned short* __restrict__ y, int n4) {
    int i = blockIdx.x * 256 + threadIdx.x;
    if (i >= n4) return;
    float4 v = ((const float4*)x)[i];
    ushort4 o;
    o.x = f2bf(v.x); o.y = f2bf(v.y); o.z = f2bf(v.z); o.w = f2bf(v.w);
    ((ushort4*)y)[i] = o;
}

// ---------------------------------------------------------------------------
// Fused 3-way MFMA GEMM (layout HW-verified by probe, rounds 6/7):
//   [C0|C1|C2] (M x 3*PW) = affine?(concat(A0,A1,A2)) (M x K) @ Bt^T + bias
// Bt: (3*PW rows) x K bf16. AFFINE folds BN scale/shift + ReLU into A staging
// (per global-k channel) — removes the separate bnapply pass.
// Block: 512 threads / 8 waves (2 row-halves x 4 col-quarters), tile 128 x NT.
// One A-tile staging feeds all 3 j-outputs (1/3 the A traffic of 3 GEMMs).
// ---------------------------------------------------------------------------
template<int PW, bool AFFINE>
__global__ __launch_bounds__(512) void k_mfma3(
    const unsigned short* __restrict__ A0, const unsigned short* __restrict__ A1,
    const unsigned short* __restrict__ A2, int W, int M, int K,
    const unsigned short* __restrict__ Bt, const float* __restrict__ bias,
    const float* __restrict__ scale, const float* __restrict__ shift,
    unsigned short* __restrict__ C0, unsigned short* __restrict__ C1,
    unsigned short* __restrict__ C2)
{
    constexpr int NT = 3 * PW;          // 384 or 192
    constexpr int TN = NT / 64;         // 6 or 3
    __shared__ __align__(16) unsigned short As[128 * 40];   // +8 pad (2-way = free)
    __shared__ __align__(16) unsigned short Bs[NT * 40];
    __shared__ float sSc[384], sSh[384];

    int t = threadIdx.x;
    if (AFFINE) {
        for (int i = t; i < K; i += 512) { sSc[i] = scale[i]; sSh[i] = shift[i]; }
    }
    __syncthreads();

    int wave = t >> 6, lane = t & 63;
    int m16 = lane & 15, q = lane >> 4;
    int rowHalf = wave & 1, colQ = wave >> 1;
    int row0 = blockIdx.x * 128;

    f4 acc[4][TN];
    #pragma unroll
    for (int i = 0; i < 4; i++)
        #pragma unroll
        for (int j = 0; j < TN; j++) acc[i][j] = (f4){0.f, 0.f, 0.f, 0.f};

    int arow_l = t >> 2, aci = t & 3;   // A: 128 rows x 4 chunks(8 bf16)
    constexpr int NCH = NT * 4;         // B chunks per K-step

    for (int kk = 0; kk < K; kk += 32) {
        int pi = kk / W;
        const unsigned short* Ap = (pi == 0) ? A0 : ((pi == 1) ? A1 : A2);
        int kl = kk - pi * W;           // piece-local k: A ONLY (B uses global kk)

        int arow = row0 + arow_l; if (arow >= M) arow = M - 1;
        uint4 av = *(const uint4*)&Ap[(size_t)arow * W + kl + aci * 8];
        if (AFFINE) {
            int ch0 = kk + aci * 8;
            unsigned int* w32 = (unsigned int*)&av;
            #pragma unroll
            for (int h = 0; h < 4; h++) {
                unsigned int u = w32[h];
                float lo = fmaxf(bf2f((unsigned short)(u & 0xffff)) * sSc[ch0 + 2*h] + sSh[ch0 + 2*h], 0.f);
                float hi = fmaxf(bf2f((unsigned short)(u >> 16))    * sSc[ch0 + 2*h + 1] + sSh[ch0 + 2*h + 1], 0.f);
                w32[h] = (unsigned int)f2bf(lo) | ((unsigned int)f2bf(hi) << 16);
            }
        }
        uint4 bvv[3]; int nb = 0;
        for (int i = t; i < NCH; i += 512) {
            int brow = i >> 2, bci = i & 3;
            bvv[nb++] = *(const uint4*)&Bt[(size_t)brow * K + kk + bci * 8];
        }
        __syncthreads();
        *(uint4*)&As[arow_l * 40 + aci * 8] = av;
        nb = 0;
        for (int i = t; i < NCH; i += 512) {
            int brow = i >> 2, bci = i & 3;
            *(uint4*)&Bs[brow * 40 + bci * 8] = bvv[nb++];
        }
        __syncthreads();

        bf8 af[4], bfr[TN];
        #pragma unroll
        for (int tm = 0; tm < 4; tm++)
            af[tm] = *(const bf8*)&As[(rowHalf * 64 + tm * 16 + m16) * 40 + q * 8];
        #pragma unroll
        for (int tn = 0; tn < TN; tn++)
            bfr[tn] = *(const bf8*)&Bs[(colQ * 16 * TN + tn * 16 + m16) * 40 + q * 8];
        #pragma unroll
        for (int tm = 0; tm < 4; tm++)
            #pragma unroll
            for (int tn = 0; tn < TN; tn++)
                acc[tm][tn] = __builtin_amdgcn_mfma_f32_16x16x32_bf16(
                    af[tm], bfr[tn], acc[tm][tn], 0, 0, 0);
    }

    #pragma unroll
    for (int tn = 0; tn < TN; tn++) {
        int col_base = colQ * 16 * TN + tn * 16;
        int j  = col_base / PW;
        int cc = col_base - j * PW + m16;
        unsigned short* Cj = (j == 0) ? C0 : ((j == 1) ? C1 : C2);
        float bi = bias[col_base + m16];
        #pragma unroll
        for (int tm = 0; tm < 4; tm++) {
            #pragma unroll
            for (int r = 0; r < 4; r++) {
                int row = row0 + rowHalf * 64 + tm * 16 + q * 4 + r;
                if (row >= M) continue;
                Cj[(size_t)row * PW + cc] = f2bf(acc[tm][tn][r] + bi);
            }
        }
    }
}

// ---------------------------------------------------------------------------
// Single-output MFMA GEMM (final projection), verified in round 7.
// C(M x 64) = concat(A0,A1,A2)(M x K, width W) @ Bt^T + bias, fp32 out.
// ---------------------------------------------------------------------------
__global__ __launch_bounds__(256) void k_mfma_fin(
    const unsigned short* __restrict__ A0, const unsigned short* __restrict__ A1,
    const unsigned short* __restrict__ A2, int W, int M, int K,
    const unsigned short* __restrict__ Bt, const float* __restrict__ bias,
    float* __restrict__ C, int ldc)
{
    constexpr int TM = 2, TN = 4;
    __shared__ __align__(16) unsigned short As[128 * 40];
    __shared__ __align__(16) unsigned short Bs[64 * 40];

    int t = threadIdx.x;
    int wave = t >> 6, lane = t & 63;
    int m16 = lane & 15, q = lane >> 4;
    int row0 = blockIdx.x * 128;
    int wr = wave * 32, wc = 0;

    f4 acc[TM][TN];
    #pragma unroll
    for (int i = 0; i < TM; i++)
        #pragma unroll
        for (int j = 0; j < TN; j++) acc[i][j] = (f4){0.f, 0.f, 0.f, 0.f};

    int ar = t & 127, ah = t >> 7;

    for (int kk = 0; kk < K; kk += 32) {
        int pi = kk / W;
        const unsigned short* Ap = (pi == 0) ? A0 : ((pi == 1) ? A1 : A2);
        int kl = kk - pi * W;

        int arow = row0 + ar; if (arow >= M) arow = M - 1;
        const uint4* asrc = (const uint4*)&Ap[(size_t)arow * W + kl + ah * 16];
        uint4 av0 = asrc[0], av1 = asrc[1];
        uint4 bv0 = *(const uint4*)&Bt[(size_t)(t & 63) * K + kk + (t >> 6) * 8];
        __syncthreads();
        *(uint4*)&As[ar * 40 + ah * 16]     = av0;
        *(uint4*)&As[ar * 40 + ah * 16 + 8] = av1;
        *(uint4*)&Bs[(t & 63) * 40 + (t >> 6) * 8] = bv0;
        __syncthreads();

        bf8 af[TM], bfr[TN];
        #pragma unroll
        for (int tm = 0; tm < TM; tm++)
            af[tm] = *(const bf8*)&As[(wr + tm * 16 + m16) * 40 + q * 8];
        #pragma unroll
        for (int tn = 0; tn < TN; tn++)
            bfr[tn] = *(const bf8*)&Bs[(wc + tn * 16 + m16) * 40 + q * 8];
        #pragma unroll
        for (int tm = 0; tm < TM; tm++)
            #pragma unroll
            for (int tn = 0; tn < TN; tn++)
                acc[tm][tn] = __builtin_amdgcn_mfma_f32_16x16x32_bf16(
                    af[tm], bfr[tn], acc[tm][tn], 0, 0, 0);
    }

    #pragma unroll
    for (int tm = 0; tm < TM; tm++) {
        #pragma unroll
        for (int tn = 0; tn < TN; tn++) {
            int col = wc + tn * 16 + m16;
            float bi = bias[col];
            #pragma unroll
            for (int r = 0; r < 4; r++) {
                int row = row0 + wr + tm * 16 + q * 4 + r;
                if (row >= M) continue;
                C[(size_t)row * ldc + col] = acc[tm][tn][r] + bi;
            }
        }
    }
}

// ---------------------------------------------------------------------------
// SpMM (bf16 in/out, fp32 accumulate), packed edges, unroll-8 (16 gathers in
// flight when DUAL). One wave per node. V=2 -> width 128, V=1 -> width 64.
// ---------------------------------------------------------------------------
template<int V, bool DUAL>
__global__ __launch_bounds__(256) void k_spmm(
    const unsigned short* __restrict__ S1, const unsigned short* __restrict__ S2,
    unsigned short* __restrict__ D1, unsigned short* __restrict__ D2, int width,
    const int* __restrict__ base, const int* __restrict__ deg,
    const int2* __restrict__ ew, int n)
{
    int node = blockIdx.x * 4 + threadIdx.y;
    if (node >= n) return;
    int tx = threadIdx.x;
    float a1[V], a2[V];
    #pragma unroll
    for (int v = 0; v < V; v++) { a1[v] = 0.f; if (DUAL) a2[v] = 0.f; }
    int b = base[node], end = b + deg[node];
    const unsigned short* P1 = S1 + tx * V;
    const unsigned short* P2 = S2 + tx * V;
    constexpr int UN = 8;
    int e = b;
    for (; e + UN <= end; e += UN) {
        int2 ev[UN];
        #pragma unroll
        for (int u = 0; u < UN; u++) ev[u] = ew[e + u];
        unsigned int g1[UN], g2[UN];
        #pragma unroll
        for (int u = 0; u < UN; u++) {
            if (V == 2) g1[u] = *(const unsigned int*)(P1 + (size_t)ev[u].x * width);
            else        g1[u] = P1[(size_t)ev[u].x * width];
            if (DUAL) {
                if (V == 2) g2[u] = *(const unsigned int*)(P2 + (size_t)ev[u].x * width);
                else        g2[u] = P2[(size_t)ev[u].x * width];
            }
        }
        #pragma unroll
        for (int u = 0; u < UN; u++) {
            float we = __int_as_float(ev[u].y);
            if (V == 2) {
                a1[0] += we * bf2f((unsigned short)(g1[u] & 0xffff));
                a1[1] += we * bf2f((unsigned short)(g1[u] >> 16));
                if (DUAL) {
                    a2[0] += we * bf2f((unsigned short)(g2[u] & 0xffff));
                    a2[1] += we * bf2f((unsigned short)(g2[u] >> 16));
                }
            } else {
                a1[0] += we * bf2f((unsigned short)g1[u]);
                if (DUAL) a2[0] += we * bf2f((unsigned short)g2[u]);
            }
        }
    }
    for (; e < end; ++e) {
        int2 ev = ew[e];
        float we = __int_as_float(ev.y);
        if (V == 2) {
            unsigned int u1 = *(const unsigned int*)(P1 + (size_t)ev.x * width);
            a1[0] += we * bf2f((unsigned short)(u1 & 0xffff));
            a1[1] += we * bf2f((unsigned short)(u1 >> 16));
            if (DUAL) {
                unsigned int u2 = *(const unsigned int*)(P2 + (size_t)ev.x * width);
                a2[0] += we * bf2f((unsigned short)(u2 & 0xffff));
                a2[1] += we * bf2f((unsigned short)(u2 >> 16));
            }
        } else {
            a1[0] += we * bf2f(P1[(size_t)ev.x * width]);
            if (DUAL) a2[0] += we * bf2f(P2[(size_t)ev.x * width]);
        }
    }
    size_t o = (size_t)node * width + tx * V;
    if (V == 2) {
        ushort2 o1; o1.x = f2bf(a1[0]); o1.y = f2bf(a1[1]);
        *(ushort2*)&D1[o] = o1;
        if (DUAL) { ushort2 o2; o2.x = f2bf(a2[0]); o2.y = f2bf(a2[1]);
                    *(ushort2*)&D2[o] = o2; }
    } else {
        D1[o] = f2bf(a1[0]);
        if (DUAL) D2[o] = f2bf(a2[0]);
    }
}

// ---------------------------------------------------------------------------
// BatchNorm batch stats over concat of 3 bf16 N x 128 pieces (apply is folded
// into the next GEMM's A-staging).
// ---------------------------------------------------------------------------
__global__ void k_bnstats(const unsigned short* __restrict__ p0,
                          const unsigned short* __restrict__ p1,
                          const unsigned short* __restrict__ p2,
                          float* __restrict__ sums, float* __restrict__ sumsq, int n)
{
    int c = threadIdx.x;
    int cc = c & 127;
    int pi = c >> 7;
    const unsigned short* src = (pi == 0) ? p0 : ((pi == 1) ? p1 : p2);
    float s = 0.f, s2 = 0.f;
    for (int r = blockIdx.x; r < n; r += gridDim.x) {
        float v = bf2f(src[(size_t)r * 128 + cc]);
        s += v; s2 += v * v;
    }
    atomicAdd(&sums[c], s);
    atomicAdd(&sumsq[c], s2);
}

__global__ void k_bnfin(const float* __restrict__ sums, const float* __restrict__ sumsq,
                        const float* __restrict__ g, const float* __restrict__ bb,
                        float* __restrict__ scale, float* __restrict__ shift,
                        int cat, float invn)
{
    int c = threadIdx.x;
    if (c >= cat) return;
    float mu  = sums[c] * invn;
    float var = sumsq[c] * invn - mu * mu;
    float sc  = g[c] * rsqrtf(var + 1e-5f);
    scale[c] = sc;
    shift[c] = bb[c] - mu * sc;
}

// Diagnostic: if workspace is too small, surface ws_size (MB) via d_out.
__global__ void k_diag(float* out, float val, int n) {
    int i = blockIdx.x * blockDim.x + threadIdx.x;
    if (i < n) out[i] = val;
}

// ---------------------------------------------------------------------------
extern "C" void kernel_launch(void* const* d_in, const int* in_sizes, int n_in,
                              void* d_out, int out_size, void* d_ws, size_t ws_size,
                              hipStream_t stream)
{
    const float* x    = (const float*)d_in[0];
    const void*  ei   = d_in[1];
    const float* W0   = (const float*)d_in[2];
    const float* b0   = (const float*)d_in[3];
    const float* W1   = (const float*)d_in[4];
    const float* b1   = (const float*)d_in[5];
    const float* W2   = (const float*)d_in[6];
    const float* b2   = (const float*)d_in[7];
    const float* bn0g = (const float*)d_in[8];
    const float* bn0b = (const float*)d_in[9];
    const float* bn1g = (const float*)d_in[10];
    const float* bn1b = (const float*)d_in[11];
    const float* fpW  = (const float*)d_in[12];
    const float* fpb  = (const float*)d_in[13];
    float* out = (float*)d_out;

    const int N    = in_sizes[0] / IN_C;
    const int twoE = in_sizes[1];
    const int E    = twoE / 2;

    // ---- workspace carve (~184 MB; budget 256 MiB) ----
    char* p = (char*)d_ws;
    auto alloc = [&](size_t bytes) -> char* {
        char* r = p; p += (bytes + 255) & ~(size_t)255; return r;
    };
    unsigned short* U[6];
    for (int i = 0; i < 6; i++) U[i] = (unsigned short*)alloc((size_t)N * 128 * 2);
    unsigned short* Wt0 = (unsigned short*)alloc((size_t)3 * 128 * 128 * 2);
    unsigned short* Wt1 = (unsigned short*)alloc((size_t)3 * 384 * 128 * 2);
    unsigned short* Wt2 = (unsigned short*)alloc((size_t)3 * 384 * 64 * 2);
    unsigned short* WtF = (unsigned short*)alloc((size_t)192 * 64 * 2);
    float* dinv  = (float*)alloc((size_t)N * 4);
    int2*  ew    = (int2*)alloc((size_t)E * 8);
    float* sums  = (float*)alloc(2 * 384 * 4);
    float* sumsq = sums + 384;
    float* scale = (float*)alloc(384 * 4);
    float* shift = (float*)alloc(384 * 4);
    int* deg     = (int*)alloc((size_t)N * 4);
    int* base    = (int*)alloc((size_t)N * 4);
    int* cursor  = (int*)alloc((size_t)N * 4);
    int* eint    = (int*)alloc((size_t)twoE * 4);
    int* counter = (int*)alloc(4);
    int* flag    = (int*)alloc(4);

    size_t required = (size_t)(p - (char*)d_ws);
    if (required > ws_size) {
        k_diag<<<(out_size + 255) / 256, 256, 0, stream>>>(
            out, (float)(ws_size >> 20), out_size);
        return;
    }

    const int T = 256;
    dim3 spmm_blk(64, 4);
    int  spmm_grid = (N + 3) / 4;
    int  gx128 = (N + 127) / 128;

    // ---- weight prep + input cast ----
    k_wprep<<<dim3((128 * 128 + 255) / 256, 3), T, 0, stream>>>(W0, Wt0, 128, 128);
    k_wprep<<<dim3((384 * 128 + 255) / 256, 3), T, 0, stream>>>(W1, Wt1, 384, 128);
    k_wprep<<<dim3((384 * 64  + 255) / 256, 3), T, 0, stream>>>(W2, Wt2, 384, 64);
    k_wprep<<<dim3((192 * 64  + 255) / 256, 1), T, 0, stream>>>(fpW, WtF, 192, 64);
    unsigned short* Xb = U[3];
    k_cast4<<<((N * 128 / 4) + 255) / 256, T, 0, stream>>>(x, Xb, N * 128 / 4);

    // ---- graph build ----
    hipMemsetAsync(deg, 0, (size_t)N * 4, stream);
    hipMemsetAsync(counter, 0, 4, stream);
    k_detect<<<1, 64, 0, stream>>>((const long long*)ei, N, flag);
    k_cvt_hist<<<(twoE + T - 1) / T, T, 0, stream>>>(ei, twoE, E, flag, eint, deg, N);
    k_dinv<<<(N + T - 1) / T, T, 0, stream>>>(deg, dinv, N);
    k_alloc<<<(N + T - 1) / T, T, 0, stream>>>(deg, base, cursor, counter, N);
    k_scatter<<<(E + T - 1) / T, T, 0, stream>>>(eint, E, dinv, N, cursor, ew);

    // ---- layer 0: Xb(=U3) -> G0:U0, G1:U1, G2:U2 (one fused GEMM) ----
    k_mfma3<128, false><<<gx128, 512, 0, stream>>>(Xb, Xb, Xb, 128, N, 128,
        Wt0, b0, nullptr, nullptr, U[0], U[1], U[2]);
    // H1 = A*G1 -> U4 ; T = A*G2 -> U5 ; H2 = A*T -> U3
    k_spmm<2, true ><<<spmm_grid, spmm_blk, 0, stream>>>(U[1], U[2], U[4], U[5], 128,
                                                         base, deg, ew, N);
    k_spmm<2, false><<<spmm_grid, spmm_blk, 0, stream>>>(U[5], nullptr, U[3], nullptr, 128,
                                                         base, deg, ew, N);
    hipMemsetAsync(sums, 0, 2 * 384 * 4, stream);
    k_bnstats<<<2048, 384, 0, stream>>>(U[0], U[4], U[3], sums, sumsq, N);
    k_bnfin<<<1, 384, 0, stream>>>(sums, sumsq, bn0g, bn0b, scale, shift, 384, 1.0f / N);
    // layer-0 raw output (U0, U4, U3); BN+ReLU folded into next GEMM A-stage.

    // ---- layer 1: affine(U0,U4,U3) -> G0:U1, G1:U2, G2:U5 ----
    k_mfma3<128, true><<<gx128, 512, 0, stream>>>(U[0], U[4], U[3], 128, N, 384,
        Wt1, b1, scale, shift, U[1], U[2], U[5]);
    // H1 = A*G1 -> U0 ; T = A*G2 -> U4 ; H2 = A*T -> U3
    k_spmm<2, true ><<<spmm_grid, spmm_blk, 0, stream>>>(U[2], U[5], U[0], U[4], 128,
                                                         base, deg, ew, N);
    k_spmm<2, false><<<spmm_grid, spmm_blk, 0, stream>>>(U[4], nullptr, U[3], nullptr, 128,
                                                         base, deg, ew, N);
    hipMemsetAsync(sums, 0, 2 * 384 * 4, stream);
    k_bnstats<<<2048, 384, 0, stream>>>(U[1], U[0], U[3], sums, sumsq, N);
    k_bnfin<<<1, 384, 0, stream>>>(sums, sumsq, bn1g, bn1b, scale, shift, 384, 1.0f / N);
    // layer-1 raw output (U1, U0, U3)

    // ---- layer 2: affine(U1,U0,U3) -> 64-wide pieces in halves of U2/U4/U5 ----
    unsigned short* V2a = U[2];
    unsigned short* V2b = U[2] + (size_t)N * 64;
    unsigned short* V4a = U[4];
    unsigned short* V4b = U[4] + (size_t)N * 64;
    unsigned short* V5a = U[5];
    unsigned short* V5b = U[5] + (size_t)N * 64;
    k_mfma3<64, true><<<gx128, 512, 0, stream>>>(U[1], U[0], U[3], 128, N, 384,
        Wt2, b2, scale, shift, V2a, V2b, V4a);
    // A*L1(V2b) -> V4b ; T = A*L2(V4a) -> V5a ; A*T -> V5b
    k_spmm<1, true ><<<spmm_grid, spmm_blk, 0, stream>>>(V2b, V4a, V4b, V5a, 64,
                                                         base, deg, ew, N);
    k_spmm<1, false><<<spmm_grid, spmm_blk, 0, stream>>>(V5a, nullptr, V5b, nullptr, 64,
                                                         base, deg, ew, N);

    // ---- final projection: out = concat(V2a, V4b, V5b)(N x 192) @ fpW + fpb ----
    k_mfma_fin<<<gx128, T, 0, stream>>>(V2a, V4b, V5b, 64, N, 192, WtF, fpb, out, 64);
}